// Round 6
// baseline (528.483 us; speedup 1.0000x reference)
//
#include <hip/hip_runtime.h>
#include <hip/hip_bf16.h>
#include <stdint.h>

typedef unsigned short u16;
typedef __attribute__((ext_vector_type(8))) short bf16x8;
typedef __attribute__((ext_vector_type(4))) float f32x4;

#define DI __device__ __forceinline__

DI float b2f(u16 u) { return __uint_as_float(((uint32_t)u) << 16); }
DI u16 f2b(float f) {
  uint32_t u = __float_as_uint(f);
  u += 0x7fff + ((u >> 16) & 1);   // RNE
  return (u16)(u >> 16);
}

DI void gld_lds16(const u16* g, u16* l) {
  __builtin_amdgcn_global_load_lds((const __attribute__((address_space(1))) void*)g,
                                   (__attribute__((address_space(3))) void*)l,
                                   16, 0, 0);
}

// ---------------------------------------------------------------------------
// Setup (one launch):
//  [0,1024)    convert 8 weight matrices (512x512 f32) -> bf16
//  [1024,1032) pack 8 biases (f32)
//  [1032,1034) bvv = Wo.bv (f32)           at bdst+4096
//  [1034,1098) Wov = Wo.Wv (f32 accum -> bf16) into weight slot 9
//  [1098,1178) zero softmax stats (20x1024 f32) at bdst+8192
// ---------------------------------------------------------------------------
__global__ __launch_bounds__(256)
void setup_wb(const float* __restrict__ w0, const float* __restrict__ w1,
              const float* __restrict__ w2, const float* __restrict__ w3,
              const float* __restrict__ w4, const float* __restrict__ w5,
              const float* __restrict__ w6, const float* __restrict__ w7,
              const float* __restrict__ b0, const float* __restrict__ b1,
              const float* __restrict__ b2, const float* __restrict__ b3,
              const float* __restrict__ b4, const float* __restrict__ b5,
              const float* __restrict__ b6, const float* __restrict__ b7,
              u16* __restrict__ dst, float* __restrict__ bdst)
{
  const int t = threadIdx.x;
  if (blockIdx.x >= 1098) {                 // zero softmax stats
    bdst[8192 + (blockIdx.x - 1098) * 256 + t] = 0.f;
    return;
  }
  if (blockIdx.x >= 1034) {                 // Wov = Wo.Wv, f32 accumulate
    const int wb = blockIdx.x - 1034;       // 64 blocks: 8x8 of 64x64 tiles
    const int a0 = (wb >> 3) * 64, b0 = (wb & 7) * 64;
    const int row = a0 + (t >> 2);
    const int bcol = b0 + (t & 3) * 16;
    float acc[16];
#pragma unroll
    for (int i = 0; i < 16; ++i) acc[i] = 0.f;
    for (int c = 0; c < 512; ++c) {
      const float woc = w3[row * 512 + c];
      const float* wvr = w2 + (long)c * 512 + bcol;
#pragma unroll
      for (int i = 0; i < 16; ++i) acc[i] += woc * wvr[i];
    }
    u16* o = dst + 9 * 262144 + (long)row * 512 + bcol;
#pragma unroll
    for (int i = 0; i < 16; ++i) o[i] = f2b(acc[i]);
    return;
  }
  if (blockIdx.x >= 1032) {                 // bvv = Wo . bv
    const int a = (blockIdx.x - 1032) * 256 + t;
    float acc = 0.f;
    for (int c = 0; c < 512; ++c) acc += w3[a * 512 + c] * b2[c];
    bdst[4096 + a] = acc;
    return;
  }
  if (blockIdx.x >= 1024) {
    const float* bs[8] = {b0, b1, b2, b3, b4, b5, b6, b7};
    const int a = blockIdx.x - 1024;
    bdst[a * 512 + t] = bs[a][t];
    bdst[a * 512 + t + 256] = bs[a][t + 256];
    return;
  }
  const float* srcs[8] = {w0, w1, w2, w3, w4, w5, w6, w7};
  const int mat = blockIdx.x >> 7;
  const int i = (((blockIdx.x & 127) << 8) + t) * 8;
  const float* s = srcs[mat];
  float4 a = *(const float4*)(s + i);
  float4 b = *(const float4*)(s + i + 4);
  alignas(16) u16 v[8] = {f2b(a.x), f2b(a.y), f2b(a.z), f2b(a.w),
                          f2b(b.x), f2b(b.y), f2b(b.z), f2b(b.w)};
  *(uint4*)(dst + (long)mat * 262144 + i) = *(const uint4*)v;
}

// ---------------------------------------------------------------------------
// Batched GEMM: BM=BN=128, BK=32, 256 threads (4 waves 2x2 of 64x64),
// 16x16x32 bf16 MFMA, XOR-swizzled LDS (0 conflicts), LDS double-buffer.
// Z-CLUSTERED XCD REMAP: flattened dispatch index g round-robins XCDs
// (XCD = g&7); idx = (g&7)*(nblk/8) + (g>>3) gives each XCD a contiguous
// run of whole z-slices -> per-XCD working set = one z's A+B panels (fits
// 4MB L2), no panel fetched by more than one XCD. Requires nblk%8==0.
// BIASMODE: 0 none, 1 bias[row], 2 bias[col].
// SMEXP: epilogue writes exp(acc*alpha), accumulates per-row sums -> stats.
// COLSCALE: epilogue multiplies col cc by 1/stats[bz*1024+cc].
// ---------------------------------------------------------------------------
template<int OUTF32, int BIASMODE, int RESID, int SMEXP, int COLSCALE>
__global__ __launch_bounds__(256)
void gemm_bt(const u16* __restrict__ A, long sA, long lda,
             const u16* __restrict__ B, long sB, long ldb,
             void* __restrict__ C, long sC,
             const float* __restrict__ bias,
             const float* __restrict__ resid, long sR,
             int N, int K, float alpha, float* __restrict__ stats)
{
  __shared__ u16 lA[2 * 128 * 32];
  __shared__ u16 lB[2 * 128 * 32];
  const int t = threadIdx.x;
  const int lane = t & 63;
  const int wid = t >> 6;

  // z-clustered XCD remap
  const uint32_t nx = gridDim.x, ny = gridDim.y;
  const uint32_t tpz = nx * ny;
  const uint32_t nblk = tpz * gridDim.z;
  const uint32_t g = ((uint32_t)blockIdx.z * ny + blockIdx.y) * nx + blockIdx.x;
  const uint32_t idx = (g & 7u) * (nblk >> 3) + (g >> 3);
  const uint32_t bz_ = idx / tpz;
  const uint32_t r   = idx - bz_ * tpz;
  const int m0 = (int)(r / nx) * 128, n0 = (int)(r % nx) * 128;
  const long bz = bz_;

  const u16* Ab = A + bz * sA;
  const u16* Bb = B + bz * sB;

  const int row = t >> 2;                              // 0..63
  const int kc  = (((t & 3) ^ ((t >> 3) & 3)) << 3);   // swizzled staged chunk

  f32x4 acc[4][4];
#pragma unroll
  for (int i = 0; i < 4; ++i)
#pragma unroll
    for (int j = 0; j < 4; ++j) acc[i][j] = (f32x4){0.f, 0.f, 0.f, 0.f};

  const int ml = lane & 15, qd = lane >> 4;
  const int koff = ((qd ^ ((ml >> 1) & 3)) << 3);      // swizzled read offset
  const int wm = (wid >> 1) * 64, wn = (wid & 1) * 64;

  auto stage = [&](int bsel, int k0) {
    const u16* Ap = Ab + (long)(m0 + row) * lda + (k0 + kc);
    const u16* Bp = Bb + (long)(n0 + row) * ldb + (k0 + kc);
    u16* la = lA + bsel * 4096 + wid * 512;
    u16* lb = lB + bsel * 4096 + wid * 512;
    gld_lds16(Ap, la);
    gld_lds16(Ap + 64 * lda, la + 2048);
    gld_lds16(Bp, lb);
    gld_lds16(Bp + 64 * ldb, lb + 2048);
  };

  const int niter = K >> 5;
  stage(0, 0);
  for (int i = 0; i < niter; ++i) {
    __syncthreads();                       // drains buf[i&1] prefetch
    if (i + 1 < niter) stage((i + 1) & 1, (i + 1) << 5);  // overlaps MFMA below
    const u16* la = lA + (i & 1) * 4096;
    const u16* lb = lB + (i & 1) * 4096;
    bf16x8 af[4], bfr[4];
#pragma unroll
    for (int x = 0; x < 4; ++x)
      af[x] = *(const bf16x8*)&la[(wm + x * 16 + ml) * 32 + koff];
#pragma unroll
    for (int y = 0; y < 4; ++y)
      bfr[y] = *(const bf16x8*)&lb[(wn + y * 16 + ml) * 32 + koff];
#pragma unroll
    for (int x = 0; x < 4; ++x)
#pragma unroll
      for (int y = 0; y < 4; ++y)
        acc[x][y] = __builtin_amdgcn_mfma_f32_16x16x32_bf16(af[x], bfr[y], acc[x][y], 0, 0, 0);
  }

  float inv[4];
  if (COLSCALE) {
#pragma unroll
    for (int j = 0; j < 4; ++j)
      inv[j] = 1.f / stats[bz * 1024 + n0 + wn + j * 16 + ml];
  }
  if (SMEXP) {
    float rs[16];
#pragma unroll
    for (int s = 0; s < 16; ++s) rs[s] = 0.f;
#pragma unroll
    for (int i = 0; i < 4; ++i)
#pragma unroll
      for (int j = 0; j < 4; ++j)
#pragma unroll
        for (int r2 = 0; r2 < 4; ++r2) {
          float e = __expf(acc[i][j][r2] * alpha);
          acc[i][j][r2] = e;
          rs[i * 4 + r2] += e;
        }
#pragma unroll
    for (int m = 1; m < 16; m <<= 1)
#pragma unroll
      for (int s = 0; s < 16; ++s) rs[s] += __shfl_xor(rs[s], m);
    if (ml == 0) {
#pragma unroll
      for (int i = 0; i < 4; ++i)
#pragma unroll
        for (int r2 = 0; r2 < 4; ++r2)
          atomicAdd(&stats[bz * 1024 + m0 + wm + i * 16 + qd * 4 + r2], rs[i * 4 + r2]);
    }
  }

  const long cb = bz * sC;
#pragma unroll
  for (int i = 0; i < 4; ++i) {
#pragma unroll
    for (int j = 0; j < 4; ++j) {
#pragma unroll
      for (int r2 = 0; r2 < 4; ++r2) {
        int rr = m0 + wm + i * 16 + qd * 4 + r2;  // C/D row = quad*4+reg (m89)
        int cc = n0 + wn + j * 16 + ml;           // C/D col = lane&15
        float v = acc[i][j][r2];
        if (!SMEXP) v *= alpha;
        if (COLSCALE) v *= inv[j];
        if (BIASMODE == 1) v += bias[rr];
        if (BIASMODE == 2) v += bias[cc];
        long ix = (long)rr * N + cc;
        if (RESID) v += resid[bz * sR + ix];
        if (OUTF32) ((float*)C)[cb + ix] = v;
        else        ((u16*)C)[cb + ix] = f2b(v);
      }
    }
  }
}

// ---------------------------------------------------------------------------
// Mega-GEMM (R2-proven, 50.2us on qkv_t): 256x256 tile, BK=32, 512 threads
// (8 waves 2Mx4N of 128x64). 4-deep LDS ring, per-phase barriers, counted
// boundary vmcnt, XOR swizzle (0 conflicts). Used ONLY for qkv_t (480 blocks).
// ---------------------------------------------------------------------------
template<int OUTF32, int BIASMODE, int RESID>
__global__ __launch_bounds__(512, 2)
void gemm256(const u16* __restrict__ A, long sA, long lda,
             const u16* __restrict__ B, long sB, long ldb,
             void* __restrict__ C, long sC,
             const float* __restrict__ bias,
             const float* __restrict__ resid, long sR,
             int N, int K, float alpha)
{
  __shared__ u16 lA[4 * 8192];
  __shared__ u16 lB[4 * 8192];
  const int t = threadIdx.x;
  const int lane = t & 63, wid = t >> 6;
  const int wr = wid >> 2, wc = wid & 3;
  const int ml = lane & 15, qd = lane >> 4;

  const int nx = gridDim.x;
  const int bid = blockIdx.y * nx + blockIdx.x;
  const int nper = (nx * gridDim.y) >> 3;
  const int nid = (bid & 7) * nper + (bid >> 3);
  const int m0 = (nid / nx) * 256, n0 = (nid % nx) * 256;

  const long bz = blockIdx.z;
  const u16* Ab = A + bz * sA;
  const u16* Bb = B + bz * sB;

  const int sw = ((lane & 3) ^ ((lane >> 3) & 3)) << 3;
  const int srow = wid * 32 + (lane >> 2);
  const u16* ApS = Ab + (long)(m0 + srow) * lda + sw;
  const u16* BpS = Bb + (long)(n0 + srow) * ldb + sw;
  u16* lwA = lA + wid * 1024;
  u16* lwB = lB + wid * 1024;

  f32x4 acc[8][4];
#pragma unroll
  for (int i = 0; i < 8; ++i)
#pragma unroll
    for (int j = 0; j < 4; ++j) acc[i][j] = (f32x4){0.f, 0.f, 0.f, 0.f};

  const int NT = K >> 5;

  auto stageA = [&](int tk) {
    const int bo = (tk & 3) << 13;
    const u16* p = ApS + ((long)tk << 5);
    gld_lds16(p,              lwA + bo);
    gld_lds16(p + (lda << 4), lwA + bo + 512);
  };
  auto stageB = [&](int tk) {
    const int bo = (tk & 3) << 13;
    const u16* p = BpS + ((long)tk << 5);
    gld_lds16(p,              lwB + bo);
    gld_lds16(p + (ldb << 4), lwB + bo + 512);
  };

  const int koff = (qd ^ ((ml >> 1) & 3)) << 3;
  const int rAo = (wr * 128 + ml) * 32 + koff;
  const int rBo = (wc * 64 + ml) * 32 + koff;

  stageA(0); stageB(0); stageA(1); stageB(1); stageA(2); stageB(2);
  asm volatile("s_waitcnt vmcnt(8)" ::: "memory");
  __builtin_amdgcn_s_barrier();
  __builtin_amdgcn_sched_barrier(0);

  for (int tk = 0; tk < NT; ++tk) {
    const int bo = (tk & 3) << 13;
    const u16* pa = lA + bo + rAo;
    const u16* pb = lB + bo + rBo;
    bf16x8 bfr[4], af[4];

#pragma unroll
    for (int n = 0; n < 4; ++n) bfr[n] = *(const bf16x8*)(pb + n * 512);
#pragma unroll
    for (int m = 0; m < 4; ++m) af[m] = *(const bf16x8*)(pa + m * 512);
    if (tk + 3 < NT) stageA(tk + 3);
    __builtin_amdgcn_sched_barrier(0);
    __builtin_amdgcn_s_barrier();
    asm volatile("s_waitcnt lgkmcnt(0)" ::: "memory");
    __builtin_amdgcn_sched_barrier(0);
    __builtin_amdgcn_s_setprio(1);
#pragma unroll
    for (int m = 0; m < 4; ++m)
#pragma unroll
      for (int n = 0; n < 4; ++n)
        acc[m][n] = __builtin_amdgcn_mfma_f32_16x16x32_bf16(af[m], bfr[n], acc[m][n], 0, 0, 0);
    __builtin_amdgcn_s_setprio(0);
    __builtin_amdgcn_sched_barrier(0);
    __builtin_amdgcn_s_barrier();
    __builtin_amdgcn_sched_barrier(0);

#pragma unroll
    for (int m = 0; m < 4; ++m) af[m] = *(const bf16x8*)(pa + (m + 4) * 512);
    if (tk + 3 < NT) stageB(tk + 3);
    __builtin_amdgcn_sched_barrier(0);
    __builtin_amdgcn_s_barrier();
    asm volatile("s_waitcnt lgkmcnt(0)" ::: "memory");
    __builtin_amdgcn_sched_barrier(0);
    __builtin_amdgcn_s_setprio(1);
#pragma unroll
    for (int m = 0; m < 4; ++m)
#pragma unroll
      for (int n = 0; n < 4; ++n)
        acc[m + 4][n] = __builtin_amdgcn_mfma_f32_16x16x32_bf16(af[m], bfr[n], acc[m + 4][n], 0, 0, 0);
    __builtin_amdgcn_s_setprio(0);
    __builtin_amdgcn_sched_barrier(0);

    if (tk < NT - 1) {
      const int rem = NT - 2 - tk;
      if (rem >= 2)      asm volatile("s_waitcnt vmcnt(8)" ::: "memory");
      else if (rem == 1) asm volatile("s_waitcnt vmcnt(4)" ::: "memory");
      else               asm volatile("s_waitcnt vmcnt(0)" ::: "memory");
      __builtin_amdgcn_s_barrier();
      __builtin_amdgcn_sched_barrier(0);
    }
  }

  const long cb = bz * sC;
#pragma unroll
  for (int mt = 0; mt < 8; ++mt) {
#pragma unroll
    for (int nt = 0; nt < 4; ++nt) {
#pragma unroll
      for (int r = 0; r < 4; ++r) {
        int rr = m0 + wr * 128 + mt * 16 + qd * 4 + r;
        int cc = n0 + wc * 64 + nt * 16 + ml;
        float v = acc[mt][nt][r] * alpha;
        if (BIASMODE == 1) v += bias[rr];
        if (BIASMODE == 2) v += bias[cc];
        long idx = (long)rr * N + cc;
        if (RESID) v += resid[bz * sR + idx];
        if (OUTF32) ((float*)C)[cb + idx] = v;
        else        ((u16*)C)[cb + idx] = f2b(v);
      }
    }
  }
}

// ---------------------------------------------------------------------------
// GroupNorm, f32 input [n][c][p] -> bf16 out TRANSPOSED to [n][p][c].
// ---------------------------------------------------------------------------
__global__ __launch_bounds__(256)
void groupnorm_f32(const float* __restrict__ x, const float* __restrict__ gamma,
                   const float* __restrict__ beta, u16* __restrict__ out)
{
  const int C = 512, HW = 1024;
  const int n = blockIdx.x >> 5, g = blockIdx.x & 31;
  const float* xg = x + ((long)n * C + g * 16) * HW;
  const int t = threadIdx.x;
  float s = 0.f, ss = 0.f;
  for (int ch = t; ch < 4096; ch += 256) {
    float4 u = *(const float4*)(xg + ch * 4);
    s += u.x + u.y + u.z + u.w;
    ss += u.x * u.x + u.y * u.y + u.z * u.z + u.w * u.w;
  }
#pragma unroll
  for (int off = 32; off > 0; off >>= 1) { s += __shfl_xor(s, off); ss += __shfl_xor(ss, off); }
  __shared__ float rs[4], rss[4];
  if ((t & 63) == 0) { rs[t >> 6] = s; rss[t >> 6] = ss; }
  __syncthreads();
  s  = rs[0] + rs[1] + rs[2] + rs[3];
  ss = rss[0] + rss[1] + rss[2] + rss[3];
  const float mu = s * (1.f / 16384.f);
  const float var = ss * (1.f / 16384.f) - mu * mu;
  const float rstd = rsqrtf(var + 1e-6f);
  float gm[16], bt[16];
#pragma unroll
  for (int i = 0; i < 16; ++i) {
    float ga = gamma[g * 16 + i];
    gm[i] = ga * rstd;
    bt[i] = beta[g * 16 + i] - mu * ga * rstd;
  }
  for (int p = t; p < 1024; p += 256) {
    alignas(16) u16 vals[16];
#pragma unroll
    for (int i = 0; i < 16; ++i)
      vals[i] = f2b(xg[(long)i * HW + p] * gm[i] + bt[i]);
    u16* dst = out + ((long)n * HW + p) * C + g * 16;
    *(uint4*)dst       = *(const uint4*)&vals[0];
    *(uint4*)(dst + 8) = *(const uint4*)&vals[8];
  }
}

// ---------------------------------------------------------------------------
// GroupNorm with fused residual: spatio = x (f32) + h (bf16 conv out), then
// GroupNorm -> bf16 out TRANSPOSED to [n][p][c].
// ---------------------------------------------------------------------------
__global__ __launch_bounds__(256)
void groupnorm_resid(const u16* __restrict__ h, const float* __restrict__ x,
                     const float* __restrict__ gamma,
                     const float* __restrict__ beta, u16* __restrict__ out)
{
  const int C = 512, HW = 1024;
  const int n = blockIdx.x >> 5, g = blockIdx.x & 31;
  const long base = ((long)n * C + g * 16) * HW;
  const float* xg = x + base;
  const u16*  hg = h + base;
  const int t = threadIdx.x;
  float s = 0.f, ss = 0.f;
  for (int ch = t; ch < 4096; ch += 256) {
    float4 u = *(const float4*)(xg + ch * 4);
    uint2 hv = *(const uint2*)(hg + ch * 4);
    float h0 = __uint_as_float(hv.x << 16);
    float h1 = __uint_as_float(hv.x & 0xffff0000u);
    float h2 = __uint_as_float(hv.y << 16);
    float h3 = __uint_as_float(hv.y & 0xffff0000u);
    float v0 = u.x + h0, v1 = u.y + h1, v2 = u.z + h2, v3 = u.w + h3;
    s += v0 + v1 + v2 + v3;
    ss += v0 * v0 + v1 * v1 + v2 * v2 + v3 * v3;
  }
#pragma unroll
  for (int off = 32; off > 0; off >>= 1) { s += __shfl_xor(s, off); ss += __shfl_xor(ss, off); }
  __shared__ float rs[4], rss[4];
  if ((t & 63) == 0) { rs[t >> 6] = s; rss[t >> 6] = ss; }
  __syncthreads();
  s  = rs[0] + rs[1] + rs[2] + rs[3];
  ss = rss[0] + rss[1] + rss[2] + rss[3];
  const float mu = s * (1.f / 16384.f);
  const float var = ss * (1.f / 16384.f) - mu * mu;
  const float rstd = rsqrtf(var + 1e-6f);
  float gm[16], bt[16];
#pragma unroll
  for (int i = 0; i < 16; ++i) {
    float ga = gamma[g * 16 + i];
    gm[i] = ga * rstd;
    bt[i] = beta[g * 16 + i] - mu * ga * rstd;
  }
  for (int p = t; p < 1024; p += 256) {
    alignas(16) u16 vals[16];
#pragma unroll
    for (int i = 0; i < 16; ++i)
      vals[i] = f2b((xg[(long)i * HW + p] + b2f(hg[(long)i * HW + p])) * gm[i] + bt[i]);
    u16* dst = out + ((long)n * HW + p) * C + g * 16;
    *(uint4*)dst       = *(const uint4*)&vals[0];
    *(uint4*)(dst + 8) = *(const uint4*)&vals[8];
  }
}

// ---------------------------------------------------------------------------
// Temporal attention: one WAVE per pixel (b,p). qkv fused [20480][1536]
// (row = q||k||v per frame/pixel). Lane l owns channels 8l..8l+7.
// ---------------------------------------------------------------------------
__global__ __launch_bounds__(256)
void temporal_attn(const u16* __restrict__ qkv, u16* __restrict__ htp)
{
  const int t = threadIdx.x;
  const int wv = t >> 6, lane = t & 63;
  const int pix = blockIdx.x * 4 + wv;      // 0..4095 = (b, p)
  const int b = pix >> 10, p = pix & 1023;
  const long fs = 1024l * 1536;             // frame stride in qkv
  const long rowbase = ((long)b * 5 * 1024 + p) * 1536 + lane * 8;

  float qf[5][8], kf[5][8];
#pragma unroll
  for (int f = 0; f < 5; ++f) {
    bf16x8 qv = *(const bf16x8*)(qkv + rowbase + f * fs);
    bf16x8 kv = *(const bf16x8*)(qkv + rowbase + f * fs + 512);
#pragma unroll
    for (int u = 0; u < 8; ++u) { qf[f][u] = b2f((u16)qv[u]); kf[f][u] = b2f((u16)kv[u]); }
  }
  float sc[25];
#pragma unroll
  for (int i = 0; i < 5; ++i)
#pragma unroll
    for (int j = 0; j < 5; ++j) {
      float a = 0.f;
#pragma unroll
      for (int u = 0; u < 8; ++u) a += qf[i][u] * kf[j][u];
      sc[i * 5 + j] = a;
    }
#pragma unroll
  for (int m = 1; m < 64; m <<= 1)
#pragma unroll
    for (int s = 0; s < 25; ++s) sc[s] += __shfl_xor(sc[s], m);

  const float scale = 0.04419417382415922f;  // 512^-0.5
  float att[5][5];
#pragma unroll
  for (int i = 0; i < 5; ++i) {
    float m = sc[i * 5];
#pragma unroll
    for (int j = 1; j < 5; ++j) m = fmaxf(m, sc[i * 5 + j]);
    float ssum = 0.f;
#pragma unroll
    for (int j = 0; j < 5; ++j) { att[i][j] = __expf((sc[i * 5 + j] - m) * scale); ssum += att[i][j]; }
    float inv = 1.f / ssum;
#pragma unroll
    for (int j = 0; j < 5; ++j) att[i][j] *= inv;
  }

  float of[5][8];
#pragma unroll
  for (int i = 0; i < 5; ++i)
#pragma unroll
    for (int u = 0; u < 8; ++u) of[i][u] = 0.f;
#pragma unroll
  for (int s = 0; s < 5; ++s) {
    bf16x8 vvv = *(const bf16x8*)(qkv + rowbase + s * fs + 1024);
#pragma unroll
    for (int u = 0; u < 8; ++u) {
      float vf = b2f((u16)vvv[u]);
#pragma unroll
      for (int i = 0; i < 5; ++i) of[i][u] += att[i][s] * vf;
    }
  }
  const long obase = ((long)b * 5 * 1024 + p) * 512 + lane * 8;
#pragma unroll
  for (int i = 0; i < 5; ++i) {
    alignas(16) u16 ob[8];
#pragma unroll
    for (int u = 0; u < 8; ++u) ob[u] = f2b(of[i][u]);
    *(uint4*)(htp + obase + i * 1024 * 512) = *(const uint4*)ob;
  }
}

// ---------------------------------------------------------------------------
extern "C" void kernel_launch(void* const* d_in, const int* in_sizes, int n_in,
                              void* d_out, int out_size, void* d_ws, size_t ws_size,
                              hipStream_t stream)
{
  const float* x   = (const float*)d_in[0];
  const float* wq  = (const float*)d_in[1];
  const float* bq  = (const float*)d_in[2];
  const float* wk  = (const float*)d_in[3];
  const float* bk  = (const float*)d_in[4];
  const float* wv  = (const float*)d_in[5];
  const float* bv  = (const float*)d_in[6];
  const float* wo  = (const float*)d_in[7];
  const float* bo  = (const float*)d_in[8];
  const float* wqt = (const float*)d_in[9];
  const float* bqt = (const float*)d_in[10];
  const float* wkt = (const float*)d_in[11];
  const float* bkt = (const float*)d_in[12];
  const float* wvt = (const float*)d_in[13];
  const float* bvt = (const float*)d_in[14];
  const float* wot = (const float*)d_in[15];
  const float* bot = (const float*)d_in[16];
  const float* gs  = (const float*)d_in[17];
  const float* bs  = (const float*)d_in[18];
  const float* gt  = (const float*)d_in[19];
  const float* btt = (const float*)d_in[20];

  // ws = 256 MiB. Slots W0..W7 (8 x 20 MB), weights Wt (10 x 0.5 MB), biases.
  const long U = 20l * 1024 * 512;          // elements per slot
  u16* W0 = (u16*)d_ws;
  u16* W1 = W0 + U;                          // W1..W3 contiguous 60 MB (qkv_t)
  u16* W3 = W0 + 3 * U;
  u16* W4 = W0 + 4 * U;                      // W4..W5 contiguous 40 MB (scores)
  u16* W6 = W0 + 6 * U;
  u16* W7 = W0 + 7 * U;
  u16* Wt = W0 + 8 * U;                      // weight slots: 0..7 = converted,
  u16* Wovs  = Wt + 9 * 262144;              // 9 = Wov = Wo.Wv
  float* Bf = (float*)(Wt + 10 * 262144);    // 8x512 biases; bvv at +4096
  float* Stats = Bf + 8192;                  // 20x1024 f32 softmax row sums
  u16* wqt_b = Wt + 4 * 262144;
  u16* wot_b = Wt + 7 * 262144;

  const long S  = 524288;                   // 1024*512 per-image stride
  const long S2 = 1048576;                  // 1024*1024 per-image stride
  const float scale = 0.04419417382415922f; // 512^-0.5
  dim3 blk(256);
  dim3 blk5(512);

  // one setup launch: weight convert + biases + bvv + Wov (f32) + stats zero
  setup_wb<<<1178, blk, 0, stream>>>(wq, wk, wv, wo, wqt, wkt, wvt, wot,
                                     bq, bk, bv, bo, bqt, bkt, bvt, bot, Wt, Bf);

  // hn = GroupNorm_s(x) -> W0 [n][p][c] (= [20480][512] row-major)
  groupnorm_f32<<<640, blk, 0, stream>>>(x, gs, bs, W0);
  // qk fused: M=20480, N=1024 (wq||wk), K=512 -> W1W2 [20480][1024]
  gemm_bt<0, 2, 0, 0, 0><<<dim3(8, 160, 1), blk, 0, stream>>>(
      W0, 0, 512, Wt, 0, 512, W1, 0, Bf, nullptr, 0, 1024, 512, 1.f, nullptr);
  // vv = Wov.hn^T + Wo.bv: batched z=20, M=c'(512), N=p(1024) -> W3 [20][c][p]
  gemm_bt<0, 1, 0, 0, 0><<<dim3(8, 4, 20), blk, 0, stream>>>(
      Wovs, 0, 512, W0, S, 512, W3, S, Bf + 4096, nullptr, 0, 1024, 512, 1.f, nullptr);
  // att_exp = exp(scale * q.k^T) -> W4W5; row sums accumulated into Stats
  gemm_bt<0, 0, 0, 1, 0><<<dim3(8, 8, 20), blk, 0, stream>>>(
      W1, S2, 1024, W1 + 512, S2, 1024, W4, S2, nullptr, nullptr, 0, 1024, 512, scale, Stats);
  // hsp_conv = (vv.att_exp^T) * inv[pq] + bo: z=20, M=c', N=pq, K=pk -> W6 [c][p]
  gemm_bt<0, 1, 0, 0, 1><<<dim3(8, 4, 20), blk, 0, stream>>>(
      W3, S, 1024, W4, S2, 1024, W6, S, Bf + 1536, nullptr, 0, 1024, 1024, 1.f, Stats);
  // hn_t = GroupNorm_t(x + W6) -> W7 [n][p][c]  (resid fused here)
  groupnorm_resid<<<640, blk, 0, stream>>>(W6, x, gt, btt, W7);
  // qkv_t fused: M=20480, N=1536 (wqt||wkt||wvt), K=512 -> W1..W3 [20480][1536]
  gemm256<0, 2, 0><<<dim3(6, 80, 1), blk5, 0, stream>>>(
      W7, 0, 512, wqt_b, 0, 512, W1, 0, Bf + 2048, nullptr, 0, 1536, 512, 1.f);
  // per-pixel 5x5 temporal attention -> W0 htp [20480][512]
  temporal_attn<<<1024, blk, 0, stream>>>(W1, W0);
  // out = x + wot.htp + bot -> d_out f32, z=20
  gemm_bt<1, 1, 1, 0, 0><<<dim3(8, 4, 20), blk, 0, stream>>>(
      wot_b, 0, 512, W0, S, 512, (float*)d_out, S, Bf + 3584, x, S, 1024, 512, 1.f, nullptr);
}

// Round 7
// 423.551 us; speedup vs baseline: 1.2477x; 1.2477x over previous
//
#include <hip/hip_runtime.h>
#include <hip/hip_bf16.h>
#include <stdint.h>

typedef unsigned short u16;
typedef __attribute__((ext_vector_type(8))) short bf16x8;
typedef __attribute__((ext_vector_type(4))) float f32x4;

#define DI __device__ __forceinline__

DI float b2f(u16 u) { return __uint_as_float(((uint32_t)u) << 16); }
DI u16 f2b(float f) {
  uint32_t u = __float_as_uint(f);
  u += 0x7fff + ((u >> 16) & 1);   // RNE
  return (u16)(u >> 16);
}

DI void gld_lds16(const u16* g, u16* l) {
  __builtin_amdgcn_global_load_lds((const __attribute__((address_space(1))) void*)g,
                                   (__attribute__((address_space(3))) void*)l,
                                   16, 0, 0);
}

// ---------------------------------------------------------------------------
// Setup (one launch):
//  [0,1024)    convert 8 weight matrices (512x512 f32) -> bf16
//              (wv additionally written TRANSPOSED to slot 8 for the Wov GEMM)
//  [1024,1032) pack 8 biases (f32)
//  [1032,1034) bvv = Wo.bv (f32)           at bdst+4096
//  [1034,1114) zero softmax stats (20x1024 f32) at bdst+8192
// Wov itself is computed by a 16-block MFMA GEMM right after (R6's in-setup
// scalar loop was 139us -- matmul belongs on the matrix cores).
// ---------------------------------------------------------------------------
__global__ __launch_bounds__(256)
void setup_wb(const float* __restrict__ w0, const float* __restrict__ w1,
              const float* __restrict__ w2, const float* __restrict__ w3,
              const float* __restrict__ w4, const float* __restrict__ w5,
              const float* __restrict__ w6, const float* __restrict__ w7,
              const float* __restrict__ b0, const float* __restrict__ b1,
              const float* __restrict__ b2, const float* __restrict__ b3,
              const float* __restrict__ b4, const float* __restrict__ b5,
              const float* __restrict__ b6, const float* __restrict__ b7,
              u16* __restrict__ dst, float* __restrict__ bdst)
{
  const int t = threadIdx.x;
  if (blockIdx.x >= 1034) {                 // zero softmax stats
    bdst[8192 + (blockIdx.x - 1034) * 256 + t] = 0.f;
    return;
  }
  if (blockIdx.x >= 1032) {                 // bvv = Wo . bv
    const int a = (blockIdx.x - 1032) * 256 + t;
    float acc = 0.f;
    for (int c = 0; c < 512; ++c) acc += w3[a * 512 + c] * b2[c];
    bdst[4096 + a] = acc;
    return;
  }
  if (blockIdx.x >= 1024) {
    const float* bs[8] = {b0, b1, b2, b3, b4, b5, b6, b7};
    const int a = blockIdx.x - 1024;
    bdst[a * 512 + t] = bs[a][t];
    bdst[a * 512 + t + 256] = bs[a][t + 256];
    return;
  }
  const float* srcs[8] = {w0, w1, w2, w3, w4, w5, w6, w7};
  const int mat = blockIdx.x >> 7;
  const int i = (((blockIdx.x & 127) << 8) + t) * 8;
  const float* s = srcs[mat];
  float4 a = *(const float4*)(s + i);
  float4 b = *(const float4*)(s + i + 4);
  alignas(16) u16 v[8] = {f2b(a.x), f2b(a.y), f2b(a.z), f2b(a.w),
                          f2b(b.x), f2b(b.y), f2b(b.z), f2b(b.w)};
  *(uint4*)(dst + (long)mat * 262144 + i) = *(const uint4*)v;
  if (mat == 2) {                           // wv: also write transpose (slot 8)
    const int row = i >> 9, col = i & 511;
#pragma unroll
    for (int j = 0; j < 8; ++j) dst[8 * 262144 + (col + j) * 512 + row] = v[j];
  }
}

// ---------------------------------------------------------------------------
// Batched GEMM: BM=BN=128, BK=32, 256 threads (4 waves 2x2 of 64x64),
// 16x16x32 bf16 MFMA, XOR-swizzled LDS (0 conflicts), LDS double-buffer.
// Z-CLUSTERED XCD REMAP: flattened dispatch index g round-robins XCDs
// (XCD = g&7); idx = (g&7)*(nblk/8) + (g>>3) gives each XCD a contiguous
// run of whole z-slices -> per-XCD working set = one z's A+B panels (fits
// 4MB L2), no panel fetched by more than one XCD. Requires nblk%8==0.
// BIASMODE: 0 none, 1 bias[row], 2 bias[col].
// SMEXP: epilogue writes exp(acc*alpha), accumulates per-row sums -> stats.
// COLSCALE: epilogue multiplies col cc by 1/stats[bz*1024+cc].
// ---------------------------------------------------------------------------
template<int OUTF32, int BIASMODE, int RESID, int SMEXP, int COLSCALE>
__global__ __launch_bounds__(256)
void gemm_bt(const u16* __restrict__ A, long sA, long lda,
             const u16* __restrict__ B, long sB, long ldb,
             void* __restrict__ C, long sC,
             const float* __restrict__ bias,
             const float* __restrict__ resid, long sR,
             int N, int K, float alpha, float* __restrict__ stats)
{
  __shared__ u16 lA[2 * 128 * 32];
  __shared__ u16 lB[2 * 128 * 32];
  const int t = threadIdx.x;
  const int lane = t & 63;
  const int wid = t >> 6;

  // z-clustered XCD remap
  const uint32_t nx = gridDim.x, ny = gridDim.y;
  const uint32_t tpz = nx * ny;
  const uint32_t nblk = tpz * gridDim.z;
  const uint32_t g = ((uint32_t)blockIdx.z * ny + blockIdx.y) * nx + blockIdx.x;
  const uint32_t idx = (g & 7u) * (nblk >> 3) + (g >> 3);
  const uint32_t bz_ = idx / tpz;
  const uint32_t r   = idx - bz_ * tpz;
  const int m0 = (int)(r / nx) * 128, n0 = (int)(r % nx) * 128;
  const long bz = bz_;

  const u16* Ab = A + bz * sA;
  const u16* Bb = B + bz * sB;

  const int row = t >> 2;                              // 0..63
  const int kc  = (((t & 3) ^ ((t >> 3) & 3)) << 3);   // swizzled staged chunk

  f32x4 acc[4][4];
#pragma unroll
  for (int i = 0; i < 4; ++i)
#pragma unroll
    for (int j = 0; j < 4; ++j) acc[i][j] = (f32x4){0.f, 0.f, 0.f, 0.f};

  const int ml = lane & 15, qd = lane >> 4;
  const int koff = ((qd ^ ((ml >> 1) & 3)) << 3);      // swizzled read offset
  const int wm = (wid >> 1) * 64, wn = (wid & 1) * 64;

  auto stage = [&](int bsel, int k0) {
    const u16* Ap = Ab + (long)(m0 + row) * lda + (k0 + kc);
    const u16* Bp = Bb + (long)(n0 + row) * ldb + (k0 + kc);
    u16* la = lA + bsel * 4096 + wid * 512;
    u16* lb = lB + bsel * 4096 + wid * 512;
    gld_lds16(Ap, la);
    gld_lds16(Ap + 64 * lda, la + 2048);
    gld_lds16(Bp, lb);
    gld_lds16(Bp + 64 * ldb, lb + 2048);
  };

  const int niter = K >> 5;
  stage(0, 0);
  for (int i = 0; i < niter; ++i) {
    __syncthreads();                       // drains buf[i&1] prefetch
    if (i + 1 < niter) stage((i + 1) & 1, (i + 1) << 5);  // overlaps MFMA below
    const u16* la = lA + (i & 1) * 4096;
    const u16* lb = lB + (i & 1) * 4096;
    bf16x8 af[4], bfr[4];
#pragma unroll
    for (int x = 0; x < 4; ++x)
      af[x] = *(const bf16x8*)&la[(wm + x * 16 + ml) * 32 + koff];
#pragma unroll
    for (int y = 0; y < 4; ++y)
      bfr[y] = *(const bf16x8*)&lb[(wn + y * 16 + ml) * 32 + koff];
#pragma unroll
    for (int x = 0; x < 4; ++x)
#pragma unroll
      for (int y = 0; y < 4; ++y)
        acc[x][y] = __builtin_amdgcn_mfma_f32_16x16x32_bf16(af[x], bfr[y], acc[x][y], 0, 0, 0);
  }

  float inv[4];
  if (COLSCALE) {
#pragma unroll
    for (int j = 0; j < 4; ++j)
      inv[j] = 1.f / stats[bz * 1024 + n0 + wn + j * 16 + ml];
  }
  if (SMEXP) {
    float rs[16];
#pragma unroll
    for (int s = 0; s < 16; ++s) rs[s] = 0.f;
#pragma unroll
    for (int i = 0; i < 4; ++i)
#pragma unroll
      for (int j = 0; j < 4; ++j)
#pragma unroll
        for (int r2 = 0; r2 < 4; ++r2) {
          float e = __expf(acc[i][j][r2] * alpha);
          acc[i][j][r2] = e;
          rs[i * 4 + r2] += e;
        }
#pragma unroll
    for (int m = 1; m < 16; m <<= 1)
#pragma unroll
      for (int s = 0; s < 16; ++s) rs[s] += __shfl_xor(rs[s], m);
    if (ml == 0) {
#pragma unroll
      for (int i = 0; i < 4; ++i)
#pragma unroll
        for (int r2 = 0; r2 < 4; ++r2)
          atomicAdd(&stats[bz * 1024 + m0 + wm + i * 16 + qd * 4 + r2], rs[i * 4 + r2]);
    }
  }

  const long cb = bz * sC;
#pragma unroll
  for (int i = 0; i < 4; ++i) {
#pragma unroll
    for (int j = 0; j < 4; ++j) {
#pragma unroll
      for (int r2 = 0; r2 < 4; ++r2) {
        int rr = m0 + wm + i * 16 + qd * 4 + r2;  // C/D row = quad*4+reg (m89)
        int cc = n0 + wn + j * 16 + ml;           // C/D col = lane&15
        float v = acc[i][j][r2];
        if (!SMEXP) v *= alpha;
        if (COLSCALE) v *= inv[j];
        if (BIASMODE == 1) v += bias[rr];
        if (BIASMODE == 2) v += bias[cc];
        long ix = (long)rr * N + cc;
        if (RESID) v += resid[bz * sR + ix];
        if (OUTF32) ((float*)C)[cb + ix] = v;
        else        ((u16*)C)[cb + ix] = f2b(v);
      }
    }
  }
}

// ---------------------------------------------------------------------------
// Mega-GEMM (R2-proven, 50.2us on qkv_t): 256x256 tile, BK=32, 512 threads
// (8 waves 2Mx4N of 128x64). 4-deep LDS ring, per-phase barriers, counted
// boundary vmcnt, XOR swizzle (0 conflicts). Used ONLY for qkv_t (480 blocks).
// ---------------------------------------------------------------------------
template<int OUTF32, int BIASMODE, int RESID>
__global__ __launch_bounds__(512, 2)
void gemm256(const u16* __restrict__ A, long sA, long lda,
             const u16* __restrict__ B, long sB, long ldb,
             void* __restrict__ C, long sC,
             const float* __restrict__ bias,
             const float* __restrict__ resid, long sR,
             int N, int K, float alpha)
{
  __shared__ u16 lA[4 * 8192];
  __shared__ u16 lB[4 * 8192];
  const int t = threadIdx.x;
  const int lane = t & 63, wid = t >> 6;
  const int wr = wid >> 2, wc = wid & 3;
  const int ml = lane & 15, qd = lane >> 4;

  const int nx = gridDim.x;
  const int bid = blockIdx.y * nx + blockIdx.x;
  const int nper = (nx * gridDim.y) >> 3;
  const int nid = (bid & 7) * nper + (bid >> 3);
  const int m0 = (nid / nx) * 256, n0 = (nid % nx) * 256;

  const long bz = blockIdx.z;
  const u16* Ab = A + bz * sA;
  const u16* Bb = B + bz * sB;

  const int sw = ((lane & 3) ^ ((lane >> 3) & 3)) << 3;
  const int srow = wid * 32 + (lane >> 2);
  const u16* ApS = Ab + (long)(m0 + srow) * lda + sw;
  const u16* BpS = Bb + (long)(n0 + srow) * ldb + sw;
  u16* lwA = lA + wid * 1024;
  u16* lwB = lB + wid * 1024;

  f32x4 acc[8][4];
#pragma unroll
  for (int i = 0; i < 8; ++i)
#pragma unroll
    for (int j = 0; j < 4; ++j) acc[i][j] = (f32x4){0.f, 0.f, 0.f, 0.f};

  const int NT = K >> 5;

  auto stageA = [&](int tk) {
    const int bo = (tk & 3) << 13;
    const u16* p = ApS + ((long)tk << 5);
    gld_lds16(p,              lwA + bo);
    gld_lds16(p + (lda << 4), lwA + bo + 512);
  };
  auto stageB = [&](int tk) {
    const int bo = (tk & 3) << 13;
    const u16* p = BpS + ((long)tk << 5);
    gld_lds16(p,              lwB + bo);
    gld_lds16(p + (ldb << 4), lwB + bo + 512);
  };

  const int koff = (qd ^ ((ml >> 1) & 3)) << 3;
  const int rAo = (wr * 128 + ml) * 32 + koff;
  const int rBo = (wc * 64 + ml) * 32 + koff;

  stageA(0); stageB(0); stageA(1); stageB(1); stageA(2); stageB(2);
  asm volatile("s_waitcnt vmcnt(8)" ::: "memory");
  __builtin_amdgcn_s_barrier();
  __builtin_amdgcn_sched_barrier(0);

  for (int tk = 0; tk < NT; ++tk) {
    const int bo = (tk & 3) << 13;
    const u16* pa = lA + bo + rAo;
    const u16* pb = lB + bo + rBo;
    bf16x8 bfr[4], af[4];

#pragma unroll
    for (int n = 0; n < 4; ++n) bfr[n] = *(const bf16x8*)(pb + n * 512);
#pragma unroll
    for (int m = 0; m < 4; ++m) af[m] = *(const bf16x8*)(pa + m * 512);
    if (tk + 3 < NT) stageA(tk + 3);
    __builtin_amdgcn_sched_barrier(0);
    __builtin_amdgcn_s_barrier();
    asm volatile("s_waitcnt lgkmcnt(0)" ::: "memory");
    __builtin_amdgcn_sched_barrier(0);
    __builtin_amdgcn_s_setprio(1);
#pragma unroll
    for (int m = 0; m < 4; ++m)
#pragma unroll
      for (int n = 0; n < 4; ++n)
        acc[m][n] = __builtin_amdgcn_mfma_f32_16x16x32_bf16(af[m], bfr[n], acc[m][n], 0, 0, 0);
    __builtin_amdgcn_s_setprio(0);
    __builtin_amdgcn_sched_barrier(0);
    __builtin_amdgcn_s_barrier();
    __builtin_amdgcn_sched_barrier(0);

#pragma unroll
    for (int m = 0; m < 4; ++m) af[m] = *(const bf16x8*)(pa + (m + 4) * 512);
    if (tk + 3 < NT) stageB(tk + 3);
    __builtin_amdgcn_sched_barrier(0);
    __builtin_amdgcn_s_barrier();
    asm volatile("s_waitcnt lgkmcnt(0)" ::: "memory");
    __builtin_amdgcn_sched_barrier(0);
    __builtin_amdgcn_s_setprio(1);
#pragma unroll
    for (int m = 0; m < 4; ++m)
#pragma unroll
      for (int n = 0; n < 4; ++n)
        acc[m + 4][n] = __builtin_amdgcn_mfma_f32_16x16x32_bf16(af[m], bfr[n], acc[m + 4][n], 0, 0, 0);
    __builtin_amdgcn_s_setprio(0);
    __builtin_amdgcn_sched_barrier(0);

    if (tk < NT - 1) {
      const int rem = NT - 2 - tk;
      if (rem >= 2)      asm volatile("s_waitcnt vmcnt(8)" ::: "memory");
      else if (rem == 1) asm volatile("s_waitcnt vmcnt(4)" ::: "memory");
      else               asm volatile("s_waitcnt vmcnt(0)" ::: "memory");
      __builtin_amdgcn_s_barrier();
      __builtin_amdgcn_sched_barrier(0);
    }
  }

  const long cb = bz * sC;
#pragma unroll
  for (int mt = 0; mt < 8; ++mt) {
#pragma unroll
    for (int nt = 0; nt < 4; ++nt) {
#pragma unroll
      for (int r = 0; r < 4; ++r) {
        int rr = m0 + wr * 128 + mt * 16 + qd * 4 + r;
        int cc = n0 + wc * 64 + nt * 16 + ml;
        float v = acc[mt][nt][r] * alpha;
        if (BIASMODE == 1) v += bias[rr];
        if (BIASMODE == 2) v += bias[cc];
        long idx = (long)rr * N + cc;
        if (RESID) v += resid[bz * sR + idx];
        if (OUTF32) ((float*)C)[cb + idx] = v;
        else        ((u16*)C)[cb + idx] = f2b(v);
      }
    }
  }
}

// ---------------------------------------------------------------------------
// GroupNorm, f32 input [n][c][p] -> bf16 out TRANSPOSED to [n][p][c].
// ---------------------------------------------------------------------------
__global__ __launch_bounds__(256)
void groupnorm_f32(const float* __restrict__ x, const float* __restrict__ gamma,
                   const float* __restrict__ beta, u16* __restrict__ out)
{
  const int C = 512, HW = 1024;
  const int n = blockIdx.x >> 5, g = blockIdx.x & 31;
  const float* xg = x + ((long)n * C + g * 16) * HW;
  const int t = threadIdx.x;
  float s = 0.f, ss = 0.f;
  for (int ch = t; ch < 4096; ch += 256) {
    float4 u = *(const float4*)(xg + ch * 4);
    s += u.x + u.y + u.z + u.w;
    ss += u.x * u.x + u.y * u.y + u.z * u.z + u.w * u.w;
  }
#pragma unroll
  for (int off = 32; off > 0; off >>= 1) { s += __shfl_xor(s, off); ss += __shfl_xor(ss, off); }
  __shared__ float rs[4], rss[4];
  if ((t & 63) == 0) { rs[t >> 6] = s; rss[t >> 6] = ss; }
  __syncthreads();
  s  = rs[0] + rs[1] + rs[2] + rs[3];
  ss = rss[0] + rss[1] + rss[2] + rss[3];
  const float mu = s * (1.f / 16384.f);
  const float var = ss * (1.f / 16384.f) - mu * mu;
  const float rstd = rsqrtf(var + 1e-6f);
  float gm[16], bt[16];
#pragma unroll
  for (int i = 0; i < 16; ++i) {
    float ga = gamma[g * 16 + i];
    gm[i] = ga * rstd;
    bt[i] = beta[g * 16 + i] - mu * ga * rstd;
  }
  for (int p = t; p < 1024; p += 256) {
    alignas(16) u16 vals[16];
#pragma unroll
    for (int i = 0; i < 16; ++i)
      vals[i] = f2b(xg[(long)i * HW + p] * gm[i] + bt[i]);
    u16* dst = out + ((long)n * HW + p) * C + g * 16;
    *(uint4*)dst       = *(const uint4*)&vals[0];
    *(uint4*)(dst + 8) = *(const uint4*)&vals[8];
  }
}

// ---------------------------------------------------------------------------
// GroupNorm with fused residual: spatio = x (f32) + h (bf16 conv out), then
// GroupNorm -> bf16 out TRANSPOSED to [n][p][c].
// ---------------------------------------------------------------------------
__global__ __launch_bounds__(256)
void groupnorm_resid(const u16* __restrict__ h, const float* __restrict__ x,
                     const float* __restrict__ gamma,
                     const float* __restrict__ beta, u16* __restrict__ out)
{
  const int C = 512, HW = 1024;
  const int n = blockIdx.x >> 5, g = blockIdx.x & 31;
  const long base = ((long)n * C + g * 16) * HW;
  const float* xg = x + base;
  const u16*  hg = h + base;
  const int t = threadIdx.x;
  float s = 0.f, ss = 0.f;
  for (int ch = t; ch < 4096; ch += 256) {
    float4 u = *(const float4*)(xg + ch * 4);
    uint2 hv = *(const uint2*)(hg + ch * 4);
    float h0 = __uint_as_float(hv.x << 16);
    float h1 = __uint_as_float(hv.x & 0xffff0000u);
    float h2 = __uint_as_float(hv.y << 16);
    float h3 = __uint_as_float(hv.y & 0xffff0000u);
    float v0 = u.x + h0, v1 = u.y + h1, v2 = u.z + h2, v3 = u.w + h3;
    s += v0 + v1 + v2 + v3;
    ss += v0 * v0 + v1 * v1 + v2 * v2 + v3 * v3;
  }
#pragma unroll
  for (int off = 32; off > 0; off >>= 1) { s += __shfl_xor(s, off); ss += __shfl_xor(ss, off); }
  __shared__ float rs[4], rss[4];
  if ((t & 63) == 0) { rs[t >> 6] = s; rss[t >> 6] = ss; }
  __syncthreads();
  s  = rs[0] + rs[1] + rs[2] + rs[3];
  ss = rss[0] + rss[1] + rss[2] + rss[3];
  const float mu = s * (1.f / 16384.f);
  const float var = ss * (1.f / 16384.f) - mu * mu;
  const float rstd = rsqrtf(var + 1e-6f);
  float gm[16], bt[16];
#pragma unroll
  for (int i = 0; i < 16; ++i) {
    float ga = gamma[g * 16 + i];
    gm[i] = ga * rstd;
    bt[i] = beta[g * 16 + i] - mu * ga * rstd;
  }
  for (int p = t; p < 1024; p += 256) {
    alignas(16) u16 vals[16];
#pragma unroll
    for (int i = 0; i < 16; ++i)
      vals[i] = f2b((xg[(long)i * HW + p] + b2f(hg[(long)i * HW + p])) * gm[i] + bt[i]);
    u16* dst = out + ((long)n * HW + p) * C + g * 16;
    *(uint4*)dst       = *(const uint4*)&vals[0];
    *(uint4*)(dst + 8) = *(const uint4*)&vals[8];
  }
}

// ---------------------------------------------------------------------------
// Temporal attention: one WAVE per pixel (b,p). qkv fused [20480][1536]
// (row = q||k||v per frame/pixel). Lane l owns channels 8l..8l+7.
// ---------------------------------------------------------------------------
__global__ __launch_bounds__(256)
void temporal_attn(const u16* __restrict__ qkv, u16* __restrict__ htp)
{
  const int t = threadIdx.x;
  const int wv = t >> 6, lane = t & 63;
  const int pix = blockIdx.x * 4 + wv;      // 0..4095 = (b, p)
  const int b = pix >> 10, p = pix & 1023;
  const long fs = 1024l * 1536;             // frame stride in qkv
  const long rowbase = ((long)b * 5 * 1024 + p) * 1536 + lane * 8;

  float qf[5][8], kf[5][8];
#pragma unroll
  for (int f = 0; f < 5; ++f) {
    bf16x8 qv = *(const bf16x8*)(qkv + rowbase + f * fs);
    bf16x8 kv = *(const bf16x8*)(qkv + rowbase + f * fs + 512);
#pragma unroll
    for (int u = 0; u < 8; ++u) { qf[f][u] = b2f((u16)qv[u]); kf[f][u] = b2f((u16)kv[u]); }
  }
  float sc[25];
#pragma unroll
  for (int i = 0; i < 5; ++i)
#pragma unroll
    for (int j = 0; j < 5; ++j) {
      float a = 0.f;
#pragma unroll
      for (int u = 0; u < 8; ++u) a += qf[i][u] * kf[j][u];
      sc[i * 5 + j] = a;
    }
#pragma unroll
  for (int m = 1; m < 64; m <<= 1)
#pragma unroll
    for (int s = 0; s < 25; ++s) sc[s] += __shfl_xor(sc[s], m);

  const float scale = 0.04419417382415922f;  // 512^-0.5
  float att[5][5];
#pragma unroll
  for (int i = 0; i < 5; ++i) {
    float m = sc[i * 5];
#pragma unroll
    for (int j = 1; j < 5; ++j) m = fmaxf(m, sc[i * 5 + j]);
    float ssum = 0.f;
#pragma unroll
    for (int j = 0; j < 5; ++j) { att[i][j] = __expf((sc[i * 5 + j] - m) * scale); ssum += att[i][j]; }
    float inv = 1.f / ssum;
#pragma unroll
    for (int j = 0; j < 5; ++j) att[i][j] *= inv;
  }

  float of[5][8];
#pragma unroll
  for (int i = 0; i < 5; ++i)
#pragma unroll
    for (int u = 0; u < 8; ++u) of[i][u] = 0.f;
#pragma unroll
  for (int s = 0; s < 5; ++s) {
    bf16x8 vvv = *(const bf16x8*)(qkv + rowbase + s * fs + 1024);
#pragma unroll
    for (int u = 0; u < 8; ++u) {
      float vf = b2f((u16)vvv[u]);
#pragma unroll
      for (int i = 0; i < 5; ++i) of[i][u] += att[i][s] * vf;
    }
  }
  const long obase = ((long)b * 5 * 1024 + p) * 512 + lane * 8;
#pragma unroll
  for (int i = 0; i < 5; ++i) {
    alignas(16) u16 ob[8];
#pragma unroll
    for (int u = 0; u < 8; ++u) ob[u] = f2b(of[i][u]);
    *(uint4*)(htp + obase + i * 1024 * 512) = *(const uint4*)ob;
  }
}

// ---------------------------------------------------------------------------
extern "C" void kernel_launch(void* const* d_in, const int* in_sizes, int n_in,
                              void* d_out, int out_size, void* d_ws, size_t ws_size,
                              hipStream_t stream)
{
  const float* x   = (const float*)d_in[0];
  const float* wq  = (const float*)d_in[1];
  const float* bq  = (const float*)d_in[2];
  const float* wk  = (const float*)d_in[3];
  const float* bk  = (const float*)d_in[4];
  const float* wv  = (const float*)d_in[5];
  const float* bv  = (const float*)d_in[6];
  const float* wo  = (const float*)d_in[7];
  const float* bo  = (const float*)d_in[8];
  const float* wqt = (const float*)d_in[9];
  const float* bqt = (const float*)d_in[10];
  const float* wkt = (const float*)d_in[11];
  const float* bkt = (const float*)d_in[12];
  const float* wvt = (const float*)d_in[13];
  const float* bvt = (const float*)d_in[14];
  const float* wot = (const float*)d_in[15];
  const float* bot = (const float*)d_in[16];
  const float* gs  = (const float*)d_in[17];
  const float* bs  = (const float*)d_in[18];
  const float* gt  = (const float*)d_in[19];
  const float* btt = (const float*)d_in[20];

  // ws = 256 MiB. Slots W0..W7 (8 x 20 MB), weights Wt (10 x 0.5 MB), biases.
  const long U = 20l * 1024 * 512;          // elements per slot
  u16* W0 = (u16*)d_ws;
  u16* W1 = W0 + U;                          // W1..W3 contiguous 60 MB (qkv_t)
  u16* W3 = W0 + 3 * U;
  u16* W4 = W0 + 4 * U;                      // W4..W5 contiguous 40 MB (scores)
  u16* W6 = W0 + 6 * U;
  u16* W7 = W0 + 7 * U;
  u16* Wt = W0 + 8 * U;                      // weight slots: 0..7 = converted,
  u16* wvT_b = Wt + 8 * 262144;              // 8 = Wv^T, 9 = Wov = Wo.Wv
  u16* Wovs  = Wt + 9 * 262144;
  float* Bf = (float*)(Wt + 10 * 262144);    // 8x512 biases; bvv at +4096
  float* Stats = Bf + 8192;                  // 20x1024 f32 softmax row sums
  u16* wo_b  = Wt + 3 * 262144;
  u16* wqt_b = Wt + 4 * 262144;
  u16* wot_b = Wt + 7 * 262144;

  const long S  = 524288;                   // 1024*512 per-image stride
  const long S2 = 1048576;                  // 1024*1024 per-image stride
  const float scale = 0.04419417382415922f; // 512^-0.5
  dim3 blk(256);
  dim3 blk5(512);

  // one setup launch: weight convert (+wvT) + biases + bvv + stats zero
  setup_wb<<<1114, blk, 0, stream>>>(wq, wk, wv, wo, wqt, wkt, wvt, wot,
                                     bq, bk, bv, bo, bqt, bkt, bvt, bot, Wt, Bf);

  // Wov = Wo . Wv on MFMA (512x512x512, ~6us): out[a][b] = sum_c wo[a][c]*WvT[b][c]
  gemm_bt<0, 0, 0, 0, 0><<<dim3(4, 4, 1), blk, 0, stream>>>(
      wo_b, 0, 512, wvT_b, 0, 512, Wovs, 0, nullptr, nullptr, 0, 512, 512, 1.f, nullptr);

  // hn = GroupNorm_s(x) -> W0 [n][p][c] (= [20480][512] row-major)
  groupnorm_f32<<<640, blk, 0, stream>>>(x, gs, bs, W0);
  // qk fused: M=20480, N=1024 (wq||wk), K=512 -> W1W2 [20480][1024]
  gemm_bt<0, 2, 0, 0, 0><<<dim3(8, 160, 1), blk, 0, stream>>>(
      W0, 0, 512, Wt, 0, 512, W1, 0, Bf, nullptr, 0, 1024, 512, 1.f, nullptr);
  // vv = Wov.hn^T + Wo.bv: batched z=20, M=c'(512), N=p(1024) -> W3 [20][c][p]
  gemm_bt<0, 1, 0, 0, 0><<<dim3(8, 4, 20), blk, 0, stream>>>(
      Wovs, 0, 512, W0, S, 512, W3, S, Bf + 4096, nullptr, 0, 1024, 512, 1.f, nullptr);
  // att_exp = exp(scale * q.k^T) -> W4W5; row sums accumulated into Stats
  gemm_bt<0, 0, 0, 1, 0><<<dim3(8, 8, 20), blk, 0, stream>>>(
      W1, S2, 1024, W1 + 512, S2, 1024, W4, S2, nullptr, nullptr, 0, 1024, 512, scale, Stats);
  // hsp_conv = (vv.att_exp^T) * inv[pq] + bo: z=20, M=c', N=pq, K=pk -> W6 [c][p]
  gemm_bt<0, 1, 0, 0, 1><<<dim3(8, 4, 20), blk, 0, stream>>>(
      W3, S, 1024, W4, S2, 1024, W6, S, Bf + 1536, nullptr, 0, 1024, 1024, 1.f, Stats);
  // hn_t = GroupNorm_t(x + W6) -> W7 [n][p][c]  (resid fused here)
  groupnorm_resid<<<640, blk, 0, stream>>>(W6, x, gt, btt, W7);
  // qkv_t fused: M=20480, N=1536 (wqt||wkt||wvt), K=512 -> W1..W3 [20480][1536]
  gemm256<0, 2, 0><<<dim3(6, 80, 1), blk5, 0, stream>>>(
      W7, 0, 512, wqt_b, 0, 512, W1, 0, Bf + 2048, nullptr, 0, 1536, 512, 1.f);
  // per-pixel 5x5 temporal attention -> W0 htp [20480][512]
  temporal_attn<<<1024, blk, 0, stream>>>(W1, W0);
  // out = x + wot.htp + bot -> d_out f32, z=20
  gemm_bt<1, 1, 1, 0, 0><<<dim3(8, 4, 20), blk, 0, stream>>>(
      wot_b, 0, 512, W0, S, 512, (float*)d_out, S, Bf + 3584, x, S, 1024, 512, 1.f, nullptr);
}

// Round 8
// 401.735 us; speedup vs baseline: 1.3155x; 1.0543x over previous
//
#include <hip/hip_runtime.h>
#include <hip/hip_bf16.h>
#include <stdint.h>

typedef unsigned short u16;
typedef __attribute__((ext_vector_type(8))) short bf16x8;
typedef __attribute__((ext_vector_type(4))) float f32x4;

#define DI __device__ __forceinline__

DI float b2f(u16 u) { return __uint_as_float(((uint32_t)u) << 16); }
DI u16 f2b(float f) {
  uint32_t u = __float_as_uint(f);
  u += 0x7fff + ((u >> 16) & 1);   // RNE
  return (u16)(u >> 16);
}

DI void gld_lds16(const u16* g, u16* l) {
  __builtin_amdgcn_global_load_lds((const __attribute__((address_space(1))) void*)g,
                                   (__attribute__((address_space(3))) void*)l,
                                   16, 0, 0);
}

// ---------------------------------------------------------------------------
// PREP (one launch; setup and GroupNorm_s are independent, so fused):
//  [0,640)      GroupNorm_s(x) -> W0 [n][p][c]. Work id XCD-remapped so
//               adjacent channel-groups (which share 64B output lines in the
//               [p][c] layout) land on the SAME XCD -> L2 merges the halves.
//  [640,1664)   convert 8 weight matrices f32->bf16 (wv also transposed ->
//               slot 8 for the Wov GEMM)
//  [1664,1672)  pack 8 biases (f32)
//  [1672,1674)  bvv = Wo.bv (f32) at bdst+4096
//  [1674,1754)  zero softmax stats (20x1024 f32) at bdst+8192
// ---------------------------------------------------------------------------
__global__ __launch_bounds__(256)
void prep(const float* __restrict__ x, const float* __restrict__ gamma,
          const float* __restrict__ beta, u16* __restrict__ gnout,
          const float* __restrict__ w0, const float* __restrict__ w1,
          const float* __restrict__ w2, const float* __restrict__ w3,
          const float* __restrict__ w4, const float* __restrict__ w5,
          const float* __restrict__ w6, const float* __restrict__ w7,
          const float* __restrict__ b0, const float* __restrict__ b1,
          const float* __restrict__ b2, const float* __restrict__ b3,
          const float* __restrict__ b4, const float* __restrict__ b5,
          const float* __restrict__ b6, const float* __restrict__ b7,
          u16* __restrict__ dst, float* __restrict__ bdst)
{
  const int t = threadIdx.x;
  if (blockIdx.x < 640) {                   // ---- GroupNorm_s ----
    const int w = (blockIdx.x & 7) * 80 + (blockIdx.x >> 3);  // XCD-cluster
    const int n = w >> 5, g = w & 31;
    const int C = 512, HW = 1024;
    const float* xg = x + ((long)n * C + g * 16) * HW;
    float s = 0.f, ss = 0.f;
    for (int ch = t; ch < 4096; ch += 256) {
      float4 u = *(const float4*)(xg + ch * 4);
      s += u.x + u.y + u.z + u.w;
      ss += u.x * u.x + u.y * u.y + u.z * u.z + u.w * u.w;
    }
#pragma unroll
    for (int off = 32; off > 0; off >>= 1) { s += __shfl_xor(s, off); ss += __shfl_xor(ss, off); }
    __shared__ float rs[4], rss[4];
    if ((t & 63) == 0) { rs[t >> 6] = s; rss[t >> 6] = ss; }
    __syncthreads();
    s  = rs[0] + rs[1] + rs[2] + rs[3];
    ss = rss[0] + rss[1] + rss[2] + rss[3];
    const float mu = s * (1.f / 16384.f);
    const float var = ss * (1.f / 16384.f) - mu * mu;
    const float rstd = rsqrtf(var + 1e-6f);
    float gm[16], bt[16];
#pragma unroll
    for (int i = 0; i < 16; ++i) {
      float ga = gamma[g * 16 + i];
      gm[i] = ga * rstd;
      bt[i] = beta[g * 16 + i] - mu * ga * rstd;
    }
    for (int p = t; p < 1024; p += 256) {
      alignas(16) u16 vals[16];
#pragma unroll
      for (int i = 0; i < 16; ++i)
        vals[i] = f2b(xg[(long)i * HW + p] * gm[i] + bt[i]);
      u16* dp = gnout + ((long)n * HW + p) * C + g * 16;
      *(uint4*)dp       = *(const uint4*)&vals[0];
      *(uint4*)(dp + 8) = *(const uint4*)&vals[8];
    }
    return;
  }
  const int sb = blockIdx.x - 640;          // ---- setup ----
  if (sb >= 1034) {                         // zero softmax stats
    bdst[8192 + (sb - 1034) * 256 + t] = 0.f;
    return;
  }
  if (sb >= 1032) {                         // bvv = Wo . bv
    const int a = (sb - 1032) * 256 + t;
    float acc = 0.f;
    for (int c = 0; c < 512; ++c) acc += w3[a * 512 + c] * b2[c];
    bdst[4096 + a] = acc;
    return;
  }
  if (sb >= 1024) {                         // biases
    const float* bs8[8] = {b0, b1, b2, b3, b4, b5, b6, b7};
    const int a = sb - 1024;
    bdst[a * 512 + t] = bs8[a][t];
    bdst[a * 512 + t + 256] = bs8[a][t + 256];
    return;
  }
  const float* srcs[8] = {w0, w1, w2, w3, w4, w5, w6, w7};
  const int mat = sb >> 7;
  const int i = (((sb & 127) << 8) + t) * 8;
  const float* s = srcs[mat];
  float4 a = *(const float4*)(s + i);
  float4 b = *(const float4*)(s + i + 4);
  alignas(16) u16 v[8] = {f2b(a.x), f2b(a.y), f2b(a.z), f2b(a.w),
                          f2b(b.x), f2b(b.y), f2b(b.z), f2b(b.w)};
  *(uint4*)(dst + (long)mat * 262144 + i) = *(const uint4*)v;
  if (mat == 2) {                           // wv: also write transpose (slot 8)
    const int row = i >> 9, col = i & 511;
#pragma unroll
    for (int j = 0; j < 8; ++j) dst[8 * 262144 + (col + j) * 512 + row] = v[j];
  }
}

// ---------------------------------------------------------------------------
// Batched GEMM: BM=BN=128, BK=32, 256 threads (4 waves 2x2 of 64x64),
// 16x16x32 bf16 MFMA, XOR-swizzled LDS (0 conflicts), LDS double-buffer.
// Z-CLUSTERED XCD REMAP: flattened dispatch index g round-robins XCDs
// (XCD = g&7); idx = (g&7)*(nblk/8) + (g>>3) gives each XCD a contiguous
// run of whole z-slices (verified R7: scores FETCH dropped off top-5).
// BIASMODE: 0 none, 1 bias[row], 2 bias[col].
// SMEXP: epilogue writes exp(acc*alpha), accumulates per-row sums -> stats.
// COLSCALE: epilogue multiplies col cc by 1/stats[bz*1024+cc].
// ---------------------------------------------------------------------------
template<int OUTF32, int BIASMODE, int RESID, int SMEXP, int COLSCALE>
__global__ __launch_bounds__(256)
void gemm_bt(const u16* __restrict__ A, long sA, long lda,
             const u16* __restrict__ B, long sB, long ldb,
             void* __restrict__ C, long sC,
             const float* __restrict__ bias,
             const float* __restrict__ resid, long sR,
             int N, int K, float alpha, float* __restrict__ stats)
{
  __shared__ u16 lA[2 * 128 * 32];
  __shared__ u16 lB[2 * 128 * 32];
  const int t = threadIdx.x;
  const int lane = t & 63;
  const int wid = t >> 6;

  // z-clustered XCD remap
  const uint32_t nx = gridDim.x, ny = gridDim.y;
  const uint32_t tpz = nx * ny;
  const uint32_t nblk = tpz * gridDim.z;
  const uint32_t g = ((uint32_t)blockIdx.z * ny + blockIdx.y) * nx + blockIdx.x;
  const uint32_t idx = (g & 7u) * (nblk >> 3) + (g >> 3);
  const uint32_t bz_ = idx / tpz;
  const uint32_t r   = idx - bz_ * tpz;
  const int m0 = (int)(r / nx) * 128, n0 = (int)(r % nx) * 128;
  const long bz = bz_;

  const u16* Ab = A + bz * sA;
  const u16* Bb = B + bz * sB;

  const int row = t >> 2;                              // 0..63
  const int kc  = (((t & 3) ^ ((t >> 3) & 3)) << 3);   // swizzled staged chunk

  f32x4 acc[4][4];
#pragma unroll
  for (int i = 0; i < 4; ++i)
#pragma unroll
    for (int j = 0; j < 4; ++j) acc[i][j] = (f32x4){0.f, 0.f, 0.f, 0.f};

  const int ml = lane & 15, qd = lane >> 4;
  const int koff = ((qd ^ ((ml >> 1) & 3)) << 3);      // swizzled read offset
  const int wm = (wid >> 1) * 64, wn = (wid & 1) * 64;

  auto stage = [&](int bsel, int k0) {
    const u16* Ap = Ab + (long)(m0 + row) * lda + (k0 + kc);
    const u16* Bp = Bb + (long)(n0 + row) * ldb + (k0 + kc);
    u16* la = lA + bsel * 4096 + wid * 512;
    u16* lb = lB + bsel * 4096 + wid * 512;
    gld_lds16(Ap, la);
    gld_lds16(Ap + 64 * lda, la + 2048);
    gld_lds16(Bp, lb);
    gld_lds16(Bp + 64 * ldb, lb + 2048);
  };

  const int niter = K >> 5;
  stage(0, 0);
  for (int i = 0; i < niter; ++i) {
    __syncthreads();                       // drains buf[i&1] prefetch
    if (i + 1 < niter) stage((i + 1) & 1, (i + 1) << 5);  // overlaps MFMA below
    const u16* la = lA + (i & 1) * 4096;
    const u16* lb = lB + (i & 1) * 4096;
    bf16x8 af[4], bfr[4];
#pragma unroll
    for (int x = 0; x < 4; ++x)
      af[x] = *(const bf16x8*)&la[(wm + x * 16 + ml) * 32 + koff];
#pragma unroll
    for (int y = 0; y < 4; ++y)
      bfr[y] = *(const bf16x8*)&lb[(wn + y * 16 + ml) * 32 + koff];
#pragma unroll
    for (int x = 0; x < 4; ++x)
#pragma unroll
      for (int y = 0; y < 4; ++y)
        acc[x][y] = __builtin_amdgcn_mfma_f32_16x16x32_bf16(af[x], bfr[y], acc[x][y], 0, 0, 0);
  }

  float inv[4];
  if (COLSCALE) {
#pragma unroll
    for (int j = 0; j < 4; ++j)
      inv[j] = 1.f / stats[bz * 1024 + n0 + wn + j * 16 + ml];
  }
  if (SMEXP) {
    float rs[16];
#pragma unroll
    for (int s = 0; s < 16; ++s) rs[s] = 0.f;
#pragma unroll
    for (int i = 0; i < 4; ++i)
#pragma unroll
      for (int j = 0; j < 4; ++j)
#pragma unroll
        for (int r2 = 0; r2 < 4; ++r2) {
          float e = __expf(acc[i][j][r2] * alpha);
          acc[i][j][r2] = e;
          rs[i * 4 + r2] += e;
        }
#pragma unroll
    for (int m = 1; m < 16; m <<= 1)
#pragma unroll
      for (int s = 0; s < 16; ++s) rs[s] += __shfl_xor(rs[s], m);
    if (ml == 0) {
#pragma unroll
      for (int i = 0; i < 4; ++i)
#pragma unroll
        for (int r2 = 0; r2 < 4; ++r2)
          atomicAdd(&stats[bz * 1024 + m0 + wm + i * 16 + qd * 4 + r2], rs[i * 4 + r2]);
    }
  }

  const long cb = bz * sC;
#pragma unroll
  for (int i = 0; i < 4; ++i) {
#pragma unroll
    for (int j = 0; j < 4; ++j) {
#pragma unroll
      for (int r2 = 0; r2 < 4; ++r2) {
        int rr = m0 + wm + i * 16 + qd * 4 + r2;  // C/D row = quad*4+reg (m89)
        int cc = n0 + wn + j * 16 + ml;           // C/D col = lane&15
        float v = acc[i][j][r2];
        if (!SMEXP) v *= alpha;
        if (COLSCALE) v *= inv[j];
        if (BIASMODE == 1) v += bias[rr];
        if (BIASMODE == 2) v += bias[cc];
        long ix = (long)rr * N + cc;
        if (RESID) v += resid[bz * sR + ix];
        if (OUTF32) ((float*)C)[cb + ix] = v;
        else        ((u16*)C)[cb + ix] = f2b(v);
      }
    }
  }
}

// ---------------------------------------------------------------------------
// Mega-GEMM (R2-proven): 256x256 tile, BK=32, 512 threads (8 waves 2Mx4N of
// 128x64). 4-deep LDS ring, per-phase barriers, counted boundary vmcnt,
// XOR swizzle (0 conflicts). Used ONLY for qkv_t (480 blocks).
// ---------------------------------------------------------------------------
template<int OUTF32, int BIASMODE, int RESID>
__global__ __launch_bounds__(512, 2)
void gemm256(const u16* __restrict__ A, long sA, long lda,
             const u16* __restrict__ B, long sB, long ldb,
             void* __restrict__ C, long sC,
             const float* __restrict__ bias,
             const float* __restrict__ resid, long sR,
             int N, int K, float alpha)
{
  __shared__ u16 lA[4 * 8192];
  __shared__ u16 lB[4 * 8192];
  const int t = threadIdx.x;
  const int lane = t & 63, wid = t >> 6;
  const int wr = wid >> 2, wc = wid & 3;
  const int ml = lane & 15, qd = lane >> 4;

  const int nx = gridDim.x;
  const int bid = blockIdx.y * nx + blockIdx.x;
  const int nper = (nx * gridDim.y) >> 3;
  const int nid = (bid & 7) * nper + (bid >> 3);
  const int m0 = (nid / nx) * 256, n0 = (nid % nx) * 256;

  const long bz = blockIdx.z;
  const u16* Ab = A + bz * sA;
  const u16* Bb = B + bz * sB;

  const int sw = ((lane & 3) ^ ((lane >> 3) & 3)) << 3;
  const int srow = wid * 32 + (lane >> 2);
  const u16* ApS = Ab + (long)(m0 + srow) * lda + sw;
  const u16* BpS = Bb + (long)(n0 + srow) * ldb + sw;
  u16* lwA = lA + wid * 1024;
  u16* lwB = lB + wid * 1024;

  f32x4 acc[8][4];
#pragma unroll
  for (int i = 0; i < 8; ++i)
#pragma unroll
    for (int j = 0; j < 4; ++j) acc[i][j] = (f32x4){0.f, 0.f, 0.f, 0.f};

  const int NT = K >> 5;

  auto stageA = [&](int tk) {
    const int bo = (tk & 3) << 13;
    const u16* p = ApS + ((long)tk << 5);
    gld_lds16(p,              lwA + bo);
    gld_lds16(p + (lda << 4), lwA + bo + 512);
  };
  auto stageB = [&](int tk) {
    const int bo = (tk & 3) << 13;
    const u16* p = BpS + ((long)tk << 5);
    gld_lds16(p,              lwB + bo);
    gld_lds16(p + (ldb << 4), lwB + bo + 512);
  };

  const int koff = (qd ^ ((ml >> 1) & 3)) << 3;
  const int rAo = (wr * 128 + ml) * 32 + koff;
  const int rBo = (wc * 64 + ml) * 32 + koff;

  stageA(0); stageB(0); stageA(1); stageB(1); stageA(2); stageB(2);
  asm volatile("s_waitcnt vmcnt(8)" ::: "memory");
  __builtin_amdgcn_s_barrier();
  __builtin_amdgcn_sched_barrier(0);

  for (int tk = 0; tk < NT; ++tk) {
    const int bo = (tk & 3) << 13;
    const u16* pa = lA + bo + rAo;
    const u16* pb = lB + bo + rBo;
    bf16x8 bfr[4], af[4];

#pragma unroll
    for (int n = 0; n < 4; ++n) bfr[n] = *(const bf16x8*)(pb + n * 512);
#pragma unroll
    for (int m = 0; m < 4; ++m) af[m] = *(const bf16x8*)(pa + m * 512);
    if (tk + 3 < NT) stageA(tk + 3);
    __builtin_amdgcn_sched_barrier(0);
    __builtin_amdgcn_s_barrier();
    asm volatile("s_waitcnt lgkmcnt(0)" ::: "memory");
    __builtin_amdgcn_sched_barrier(0);
    __builtin_amdgcn_s_setprio(1);
#pragma unroll
    for (int m = 0; m < 4; ++m)
#pragma unroll
      for (int n = 0; n < 4; ++n)
        acc[m][n] = __builtin_amdgcn_mfma_f32_16x16x32_bf16(af[m], bfr[n], acc[m][n], 0, 0, 0);
    __builtin_amdgcn_s_setprio(0);
    __builtin_amdgcn_sched_barrier(0);
    __builtin_amdgcn_s_barrier();
    __builtin_amdgcn_sched_barrier(0);

#pragma unroll
    for (int m = 0; m < 4; ++m) af[m] = *(const bf16x8*)(pa + (m + 4) * 512);
    if (tk + 3 < NT) stageB(tk + 3);
    __builtin_amdgcn_sched_barrier(0);
    __builtin_amdgcn_s_barrier();
    asm volatile("s_waitcnt lgkmcnt(0)" ::: "memory");
    __builtin_amdgcn_sched_barrier(0);
    __builtin_amdgcn_s_setprio(1);
#pragma unroll
    for (int m = 0; m < 4; ++m)
#pragma unroll
      for (int n = 0; n < 4; ++n)
        acc[m + 4][n] = __builtin_amdgcn_mfma_f32_16x16x32_bf16(af[m], bfr[n], acc[m + 4][n], 0, 0, 0);
    __builtin_amdgcn_s_setprio(0);
    __builtin_amdgcn_sched_barrier(0);

    if (tk < NT - 1) {
      const int rem = NT - 2 - tk;
      if (rem >= 2)      asm volatile("s_waitcnt vmcnt(8)" ::: "memory");
      else if (rem == 1) asm volatile("s_waitcnt vmcnt(4)" ::: "memory");
      else               asm volatile("s_waitcnt vmcnt(0)" ::: "memory");
      __builtin_amdgcn_s_barrier();
      __builtin_amdgcn_sched_barrier(0);
    }
  }

  const long cb = bz * sC;
#pragma unroll
  for (int mt = 0; mt < 8; ++mt) {
#pragma unroll
    for (int nt = 0; nt < 4; ++nt) {
#pragma unroll
      for (int r = 0; r < 4; ++r) {
        int rr = m0 + wr * 128 + mt * 16 + qd * 4 + r;
        int cc = n0 + wc * 64 + nt * 16 + ml;
        float v = acc[mt][nt][r] * alpha;
        if (BIASMODE == 1) v += bias[rr];
        if (BIASMODE == 2) v += bias[cc];
        long idx = (long)rr * N + cc;
        if (RESID) v += resid[bz * sR + idx];
        if (OUTF32) ((float*)C)[cb + idx] = v;
        else        ((u16*)C)[cb + idx] = f2b(v);
      }
    }
  }
}

// ---------------------------------------------------------------------------
// GroupNorm with fused residual: spatio = x (f32) + h (bf16 conv out), then
// GroupNorm -> bf16 out TRANSPOSED to [n][p][c]. Work id XCD-remapped (same
// rationale as prep's gn part).
// ---------------------------------------------------------------------------
__global__ __launch_bounds__(256)
void groupnorm_resid(const u16* __restrict__ h, const float* __restrict__ x,
                     const float* __restrict__ gamma,
                     const float* __restrict__ beta, u16* __restrict__ out)
{
  const int C = 512, HW = 1024;
  const int w = (blockIdx.x & 7) * 80 + (blockIdx.x >> 3);    // XCD-cluster
  const int n = w >> 5, g = w & 31;
  const long base = ((long)n * C + g * 16) * HW;
  const float* xg = x + base;
  const u16*  hg = h + base;
  const int t = threadIdx.x;
  float s = 0.f, ss = 0.f;
  for (int ch = t; ch < 4096; ch += 256) {
    float4 u = *(const float4*)(xg + ch * 4);
    uint2 hv = *(const uint2*)(hg + ch * 4);
    float h0 = __uint_as_float(hv.x << 16);
    float h1 = __uint_as_float(hv.x & 0xffff0000u);
    float h2 = __uint_as_float(hv.y << 16);
    float h3 = __uint_as_float(hv.y & 0xffff0000u);
    float v0 = u.x + h0, v1 = u.y + h1, v2 = u.z + h2, v3 = u.w + h3;
    s += v0 + v1 + v2 + v3;
    ss += v0 * v0 + v1 * v1 + v2 * v2 + v3 * v3;
  }
#pragma unroll
  for (int off = 32; off > 0; off >>= 1) { s += __shfl_xor(s, off); ss += __shfl_xor(ss, off); }
  __shared__ float rs[4], rss[4];
  if ((t & 63) == 0) { rs[t >> 6] = s; rss[t >> 6] = ss; }
  __syncthreads();
  s  = rs[0] + rs[1] + rs[2] + rs[3];
  ss = rss[0] + rss[1] + rss[2] + rss[3];
  const float mu = s * (1.f / 16384.f);
  const float var = ss * (1.f / 16384.f) - mu * mu;
  const float rstd = rsqrtf(var + 1e-6f);
  float gm[16], bt[16];
#pragma unroll
  for (int i = 0; i < 16; ++i) {
    float ga = gamma[g * 16 + i];
    gm[i] = ga * rstd;
    bt[i] = beta[g * 16 + i] - mu * ga * rstd;
  }
  for (int p = t; p < 1024; p += 256) {
    alignas(16) u16 vals[16];
#pragma unroll
    for (int i = 0; i < 16; ++i)
      vals[i] = f2b((xg[(long)i * HW + p] + b2f(hg[(long)i * HW + p])) * gm[i] + bt[i]);
    u16* dst = out + ((long)n * HW + p) * C + g * 16;
    *(uint4*)dst       = *(const uint4*)&vals[0];
    *(uint4*)(dst + 8) = *(const uint4*)&vals[8];
  }
}

// ---------------------------------------------------------------------------
// Temporal attention: one WAVE per pixel (b,p). qkv fused [20480][1536]
// (row = q||k||v per frame/pixel). Lane l owns channels 8l..8l+7.
// ---------------------------------------------------------------------------
__global__ __launch_bounds__(256)
void temporal_attn(const u16* __restrict__ qkv, u16* __restrict__ htp)
{
  const int t = threadIdx.x;
  const int wv = t >> 6, lane = t & 63;
  const int pix = blockIdx.x * 4 + wv;      // 0..4095 = (b, p)
  const int b = pix >> 10, p = pix & 1023;
  const long fs = 1024l * 1536;             // frame stride in qkv
  const long rowbase = ((long)b * 5 * 1024 + p) * 1536 + lane * 8;

  float qf[5][8], kf[5][8];
#pragma unroll
  for (int f = 0; f < 5; ++f) {
    bf16x8 qv = *(const bf16x8*)(qkv + rowbase + f * fs);
    bf16x8 kv = *(const bf16x8*)(qkv + rowbase + f * fs + 512);
#pragma unroll
    for (int u = 0; u < 8; ++u) { qf[f][u] = b2f((u16)qv[u]); kf[f][u] = b2f((u16)kv[u]); }
  }
  float sc[25];
#pragma unroll
  for (int i = 0; i < 5; ++i)
#pragma unroll
    for (int j = 0; j < 5; ++j) {
      float a = 0.f;
#pragma unroll
      for (int u = 0; u < 8; ++u) a += qf[i][u] * kf[j][u];
      sc[i * 5 + j] = a;
    }
#pragma unroll
  for (int m = 1; m < 64; m <<= 1)
#pragma unroll
    for (int s = 0; s < 25; ++s) sc[s] += __shfl_xor(sc[s], m);

  const float scale = 0.04419417382415922f;  // 512^-0.5
  float att[5][5];
#pragma unroll
  for (int i = 0; i < 5; ++i) {
    float m = sc[i * 5];
#pragma unroll
    for (int j = 1; j < 5; ++j) m = fmaxf(m, sc[i * 5 + j]);
    float ssum = 0.f;
#pragma unroll
    for (int j = 0; j < 5; ++j) { att[i][j] = __expf((sc[i * 5 + j] - m) * scale); ssum += att[i][j]; }
    float inv = 1.f / ssum;
#pragma unroll
    for (int j = 0; j < 5; ++j) att[i][j] *= inv;
  }

  float of[5][8];
#pragma unroll
  for (int i = 0; i < 5; ++i)
#pragma unroll
    for (int u = 0; u < 8; ++u) of[i][u] = 0.f;
#pragma unroll
  for (int s = 0; s < 5; ++s) {
    bf16x8 vvv = *(const bf16x8*)(qkv + rowbase + s * fs + 1024);
#pragma unroll
    for (int u = 0; u < 8; ++u) {
      float vf = b2f((u16)vvv[u]);
#pragma unroll
      for (int i = 0; i < 5; ++i) of[i][u] += att[i][s] * vf;
    }
  }
  const long obase = ((long)b * 5 * 1024 + p) * 512 + lane * 8;
#pragma unroll
  for (int i = 0; i < 5; ++i) {
    alignas(16) u16 ob[8];
#pragma unroll
    for (int u = 0; u < 8; ++u) ob[u] = f2b(of[i][u]);
    *(uint4*)(htp + obase + i * 1024 * 512) = *(const uint4*)ob;
  }
}

// ---------------------------------------------------------------------------
extern "C" void kernel_launch(void* const* d_in, const int* in_sizes, int n_in,
                              void* d_out, int out_size, void* d_ws, size_t ws_size,
                              hipStream_t stream)
{
  const float* x   = (const float*)d_in[0];
  const float* wq  = (const float*)d_in[1];
  const float* bq  = (const float*)d_in[2];
  const float* wk  = (const float*)d_in[3];
  const float* bk  = (const float*)d_in[4];
  const float* wv  = (const float*)d_in[5];
  const float* bv  = (const float*)d_in[6];
  const float* wo  = (const float*)d_in[7];
  const float* bo  = (const float*)d_in[8];
  const float* wqt = (const float*)d_in[9];
  const float* bqt = (const float*)d_in[10];
  const float* wkt = (const float*)d_in[11];
  const float* bkt = (const float*)d_in[12];
  const float* wvt = (const float*)d_in[13];
  const float* bvt = (const float*)d_in[14];
  const float* wot = (const float*)d_in[15];
  const float* bot = (const float*)d_in[16];
  const float* gs  = (const float*)d_in[17];
  const float* bs  = (const float*)d_in[18];
  const float* gt  = (const float*)d_in[19];
  const float* btt = (const float*)d_in[20];

  // ws = 256 MiB. Slots W0..W7 (8 x 20 MB), weights Wt (10 x 0.5 MB), biases.
  const long U = 20l * 1024 * 512;          // elements per slot
  u16* W0 = (u16*)d_ws;
  u16* W1 = W0 + U;                          // W1..W3 contiguous 60 MB (qkv_t)
  u16* W3 = W0 + 3 * U;
  u16* W4 = W0 + 4 * U;                      // W4..W5 contiguous 40 MB (scores)
  u16* W6 = W0 + 6 * U;
  u16* W7 = W0 + 7 * U;
  u16* Wt = W0 + 8 * U;                      // weight slots: 0..7 = converted,
  u16* wvT_b = Wt + 8 * 262144;              // 8 = Wv^T, 9 = Wov = Wo.Wv
  u16* Wovs  = Wt + 9 * 262144;
  float* Bf = (float*)(Wt + 10 * 262144);    // 8x512 biases; bvv at +4096
  float* Stats = Bf + 8192;                  // 20x1024 f32 softmax row sums
  u16* wo_b  = Wt + 3 * 262144;
  u16* wqt_b = Wt + 4 * 262144;
  u16* wot_b = Wt + 7 * 262144;

  const long S  = 524288;                   // 1024*512 per-image stride
  const long S2 = 1048576;                  // 1024*1024 per-image stride
  const float scale = 0.04419417382415922f; // 512^-0.5
  dim3 blk(256);
  dim3 blk5(512);

  // prep: GroupNorm_s + weight convert (+wvT) + biases + bvv + stats zero
  prep<<<1754, blk, 0, stream>>>(x, gs, bs, W0,
                                 wq, wk, wv, wo, wqt, wkt, wvt, wot,
                                 bq, bk, bv, bo, bqt, bkt, bvt, bot, Wt, Bf);

  // Wov = Wo . Wv on MFMA (512x512x512): out[a][b] = sum_c wo[a][c]*WvT[b][c]
  gemm_bt<0, 0, 0, 0, 0><<<dim3(4, 4, 1), blk, 0, stream>>>(
      wo_b, 0, 512, wvT_b, 0, 512, Wovs, 0, nullptr, nullptr, 0, 512, 512, 1.f, nullptr);

  // qk fused: M=20480, N=1024 (wq||wk), K=512 -> W1W2 [20480][1024]
  gemm_bt<0, 2, 0, 0, 0><<<dim3(8, 160, 1), blk, 0, stream>>>(
      W0, 0, 512, Wt, 0, 512, W1, 0, Bf, nullptr, 0, 1024, 512, 1.f, nullptr);
  // vv = Wov.hn^T + Wo.bv: batched z=20, M=c'(512), N=p(1024) -> W3 [20][c][p]
  gemm_bt<0, 1, 0, 0, 0><<<dim3(8, 4, 20), blk, 0, stream>>>(
      Wovs, 0, 512, W0, S, 512, W3, S, Bf + 4096, nullptr, 0, 1024, 512, 1.f, nullptr);
  // att_exp = exp(scale * q.k^T) -> W4W5; row sums accumulated into Stats
  gemm_bt<0, 0, 0, 1, 0><<<dim3(8, 8, 20), blk, 0, stream>>>(
      W1, S2, 1024, W1 + 512, S2, 1024, W4, S2, nullptr, nullptr, 0, 1024, 512, scale, Stats);
  // hsp_conv = (vv.att_exp^T) * inv[pq] + bo: z=20, M=c', N=pq, K=pk -> W6 [c][p]
  gemm_bt<0, 1, 0, 0, 1><<<dim3(8, 4, 20), blk, 0, stream>>>(
      W3, S, 1024, W4, S2, 1024, W6, S, Bf + 1536, nullptr, 0, 1024, 1024, 1.f, Stats);
  // hn_t = GroupNorm_t(x + W6) -> W7 [n][p][c]  (resid fused here)
  groupnorm_resid<<<640, blk, 0, stream>>>(W6, x, gt, btt, W7);
  // qkv_t fused: M=20480, N=1536 (wqt||wkt||wvt), K=512 -> W1..W3 [20480][1536]
  gemm256<0, 2, 0><<<dim3(6, 80, 1), blk5, 0, stream>>>(
      W7, 0, 512, wqt_b, 0, 512, W1, 0, Bf + 2048, nullptr, 0, 1536, 512, 1.f);
  // per-pixel 5x5 temporal attention -> W0 htp [20480][512]
  temporal_attn<<<1024, blk, 0, stream>>>(W1, W0);
  // out = x + wot.htp + bot -> d_out f32, z=20
  gemm_bt<1, 1, 1, 0, 0><<<dim3(8, 4, 20), blk, 0, stream>>>(
      wot_b, 0, 512, W0, S, 512, (float*)d_out, S, Bf + 3584, x, S, 1024, 512, 1.f, nullptr);
}

// Round 9
// 391.850 us; speedup vs baseline: 1.3487x; 1.0252x over previous
//
#include <hip/hip_runtime.h>
#include <hip/hip_bf16.h>
#include <stdint.h>

typedef unsigned short u16;
typedef __attribute__((ext_vector_type(8))) short bf16x8;
typedef __attribute__((ext_vector_type(4))) float f32x4;

#define DI __device__ __forceinline__

DI float b2f(u16 u) { return __uint_as_float(((uint32_t)u) << 16); }
DI u16 f2b(float f) {
  uint32_t u = __float_as_uint(f);
  u += 0x7fff + ((u >> 16) & 1);   // RNE
  return (u16)(u >> 16);
}

DI void gld_lds16(const u16* g, u16* l) {
  __builtin_amdgcn_global_load_lds((const __attribute__((address_space(1))) void*)g,
                                   (__attribute__((address_space(3))) void*)l,
                                   16, 0, 0);
}

// ---------------------------------------------------------------------------
// PREP (one launch):
//  [0,640)      GroupNorm_s(x) -> W0 [n][p][c] (XCD-clustered work ids)
//  [640,1664)   convert 8 weight matrices f32->bf16
//               (wv transposed -> slot 8; wvt transposed -> slot 10)
//  [1664,1672)  pack 8 biases (f32)
//  [1672,1674)  bvv  = Wo.bv            (f32) at bdst+4096
//  [1674,1676)  bovt = Wot.bvt + bot    (f32) at bdst+4608
//  [1676,1756)  zero softmax stats (20x1024 f32) at bdst+8192
// ---------------------------------------------------------------------------
__global__ __launch_bounds__(256)
void prep(const float* __restrict__ x, const float* __restrict__ gamma,
          const float* __restrict__ beta, u16* __restrict__ gnout,
          const float* __restrict__ w0, const float* __restrict__ w1,
          const float* __restrict__ w2, const float* __restrict__ w3,
          const float* __restrict__ w4, const float* __restrict__ w5,
          const float* __restrict__ w6, const float* __restrict__ w7,
          const float* __restrict__ b0, const float* __restrict__ b1,
          const float* __restrict__ b2, const float* __restrict__ b3,
          const float* __restrict__ b4, const float* __restrict__ b5,
          const float* __restrict__ b6, const float* __restrict__ b7,
          u16* __restrict__ dst, float* __restrict__ bdst)
{
  const int t = threadIdx.x;
  if (blockIdx.x < 640) {                   // ---- GroupNorm_s ----
    const int w = (blockIdx.x & 7) * 80 + (blockIdx.x >> 3);  // XCD-cluster
    const int n = w >> 5, g = w & 31;
    const int C = 512, HW = 1024;
    const float* xg = x + ((long)n * C + g * 16) * HW;
    float s = 0.f, ss = 0.f;
    for (int ch = t; ch < 4096; ch += 256) {
      float4 u = *(const float4*)(xg + ch * 4);
      s += u.x + u.y + u.z + u.w;
      ss += u.x * u.x + u.y * u.y + u.z * u.z + u.w * u.w;
    }
#pragma unroll
    for (int off = 32; off > 0; off >>= 1) { s += __shfl_xor(s, off); ss += __shfl_xor(ss, off); }
    __shared__ float rs[4], rss[4];
    if ((t & 63) == 0) { rs[t >> 6] = s; rss[t >> 6] = ss; }
    __syncthreads();
    s  = rs[0] + rs[1] + rs[2] + rs[3];
    ss = rss[0] + rss[1] + rss[2] + rss[3];
    const float mu = s * (1.f / 16384.f);
    const float var = ss * (1.f / 16384.f) - mu * mu;
    const float rstd = rsqrtf(var + 1e-6f);
    float gm[16], bt[16];
#pragma unroll
    for (int i = 0; i < 16; ++i) {
      float ga = gamma[g * 16 + i];
      gm[i] = ga * rstd;
      bt[i] = beta[g * 16 + i] - mu * ga * rstd;
    }
    for (int p = t; p < 1024; p += 256) {
      alignas(16) u16 vals[16];
#pragma unroll
      for (int i = 0; i < 16; ++i)
        vals[i] = f2b(xg[(long)i * HW + p] * gm[i] + bt[i]);
      u16* dp = gnout + ((long)n * HW + p) * C + g * 16;
      *(uint4*)dp       = *(const uint4*)&vals[0];
      *(uint4*)(dp + 8) = *(const uint4*)&vals[8];
    }
    return;
  }
  const int sb = blockIdx.x - 640;          // ---- setup ----
  if (sb >= 1036) {                         // zero softmax stats
    bdst[8192 + (sb - 1036) * 256 + t] = 0.f;
    return;
  }
  if (sb >= 1034) {                         // bovt = Wot.bvt + bot
    const int a = (sb - 1034) * 256 + t;
    float acc = 0.f;
    for (int c = 0; c < 512; ++c) acc += w7[a * 512 + c] * b6[c];
    bdst[4608 + a] = acc + b7[a];
    return;
  }
  if (sb >= 1032) {                         // bvv = Wo . bv
    const int a = (sb - 1032) * 256 + t;
    float acc = 0.f;
    for (int c = 0; c < 512; ++c) acc += w3[a * 512 + c] * b2[c];
    bdst[4096 + a] = acc;
    return;
  }
  if (sb >= 1024) {                         // biases
    const float* bs8[8] = {b0, b1, b2, b3, b4, b5, b6, b7};
    const int a = sb - 1024;
    bdst[a * 512 + t] = bs8[a][t];
    bdst[a * 512 + t + 256] = bs8[a][t + 256];
    return;
  }
  const float* srcs[8] = {w0, w1, w2, w3, w4, w5, w6, w7};
  const int mat = sb >> 7;
  const int i = (((sb & 127) << 8) + t) * 8;
  const float* s = srcs[mat];
  float4 a = *(const float4*)(s + i);
  float4 b = *(const float4*)(s + i + 4);
  alignas(16) u16 v[8] = {f2b(a.x), f2b(a.y), f2b(a.z), f2b(a.w),
                          f2b(b.x), f2b(b.y), f2b(b.z), f2b(b.w)};
  *(uint4*)(dst + (long)mat * 262144 + i) = *(const uint4*)v;
  if (mat == 2 || mat == 6) {               // wv -> slot 8, wvt -> slot 10
    const int slot = (mat == 2) ? 8 : 10;
    const int row = i >> 9, col = i & 511;
#pragma unroll
    for (int j = 0; j < 8; ++j) dst[(long)slot * 262144 + (col + j) * 512 + row] = v[j];
  }
}

// ---------------------------------------------------------------------------
// Batched GEMM: BM=BN=128, BK=32, 256 threads (4 waves 2x2 of 64x64),
// 16x16x32 bf16 MFMA, XOR-swizzled LDS (0 conflicts), LDS double-buffer.
// Z-CLUSTERED XCD REMAP (verified R7: scores FETCH 92->off-top-5).
// BIASMODE: 0 none, 1 bias[row], 2 bias[col].
// SMEXP: epilogue writes exp(acc*alpha), accumulates per-row sums -> stats.
// COLSCALE: epilogue multiplies col cc by 1/stats[bz*1024+cc].
// ---------------------------------------------------------------------------
template<int OUTF32, int BIASMODE, int RESID, int SMEXP, int COLSCALE>
__global__ __launch_bounds__(256)
void gemm_bt(const u16* __restrict__ A, long sA, long lda,
             const u16* __restrict__ B, long sB, long ldb,
             void* __restrict__ C, long sC,
             const float* __restrict__ bias,
             const float* __restrict__ resid, long sR,
             int N, int K, float alpha, float* __restrict__ stats)
{
  __shared__ u16 lA[2 * 128 * 32];
  __shared__ u16 lB[2 * 128 * 32];
  const int t = threadIdx.x;
  const int lane = t & 63;
  const int wid = t >> 6;

  // z-clustered XCD remap
  const uint32_t nx = gridDim.x, ny = gridDim.y;
  const uint32_t tpz = nx * ny;
  const uint32_t nblk = tpz * gridDim.z;
  const uint32_t g = ((uint32_t)blockIdx.z * ny + blockIdx.y) * nx + blockIdx.x;
  const uint32_t idx = (g & 7u) * (nblk >> 3) + (g >> 3);
  const uint32_t bz_ = idx / tpz;
  const uint32_t r   = idx - bz_ * tpz;
  const int m0 = (int)(r / nx) * 128, n0 = (int)(r % nx) * 128;
  const long bz = bz_;

  const u16* Ab = A + bz * sA;
  const u16* Bb = B + bz * sB;

  const int row = t >> 2;                              // 0..63
  const int kc  = (((t & 3) ^ ((t >> 3) & 3)) << 3);   // swizzled staged chunk

  f32x4 acc[4][4];
#pragma unroll
  for (int i = 0; i < 4; ++i)
#pragma unroll
    for (int j = 0; j < 4; ++j) acc[i][j] = (f32x4){0.f, 0.f, 0.f, 0.f};

  const int ml = lane & 15, qd = lane >> 4;
  const int koff = ((qd ^ ((ml >> 1) & 3)) << 3);      // swizzled read offset
  const int wm = (wid >> 1) * 64, wn = (wid & 1) * 64;

  auto stage = [&](int bsel, int k0) {
    const u16* Ap = Ab + (long)(m0 + row) * lda + (k0 + kc);
    const u16* Bp = Bb + (long)(n0 + row) * ldb + (k0 + kc);
    u16* la = lA + bsel * 4096 + wid * 512;
    u16* lb = lB + bsel * 4096 + wid * 512;
    gld_lds16(Ap, la);
    gld_lds16(Ap + 64 * lda, la + 2048);
    gld_lds16(Bp, lb);
    gld_lds16(Bp + 64 * ldb, lb + 2048);
  };

  const int niter = K >> 5;
  stage(0, 0);
  for (int i = 0; i < niter; ++i) {
    __syncthreads();                       // drains buf[i&1] prefetch
    if (i + 1 < niter) stage((i + 1) & 1, (i + 1) << 5);  // overlaps MFMA below
    const u16* la = lA + (i & 1) * 4096;
    const u16* lb = lB + (i & 1) * 4096;
    bf16x8 af[4], bfr[4];
#pragma unroll
    for (int x = 0; x < 4; ++x)
      af[x] = *(const bf16x8*)&la[(wm + x * 16 + ml) * 32 + koff];
#pragma unroll
    for (int y = 0; y < 4; ++y)
      bfr[y] = *(const bf16x8*)&lb[(wn + y * 16 + ml) * 32 + koff];
#pragma unroll
    for (int x = 0; x < 4; ++x)
#pragma unroll
      for (int y = 0; y < 4; ++y)
        acc[x][y] = __builtin_amdgcn_mfma_f32_16x16x32_bf16(af[x], bfr[y], acc[x][y], 0, 0, 0);
  }

  float inv[4];
  if (COLSCALE) {
#pragma unroll
    for (int j = 0; j < 4; ++j)
      inv[j] = 1.f / stats[bz * 1024 + n0 + wn + j * 16 + ml];
  }
  if (SMEXP) {
    float rs[16];
#pragma unroll
    for (int s = 0; s < 16; ++s) rs[s] = 0.f;
#pragma unroll
    for (int i = 0; i < 4; ++i)
#pragma unroll
      for (int j = 0; j < 4; ++j)
#pragma unroll
        for (int r2 = 0; r2 < 4; ++r2) {
          float e = __expf(acc[i][j][r2] * alpha);
          acc[i][j][r2] = e;
          rs[i * 4 + r2] += e;
        }
#pragma unroll
    for (int m = 1; m < 16; m <<= 1)
#pragma unroll
      for (int s = 0; s < 16; ++s) rs[s] += __shfl_xor(rs[s], m);
    if (ml == 0) {
#pragma unroll
      for (int i = 0; i < 4; ++i)
#pragma unroll
        for (int r2 = 0; r2 < 4; ++r2)
          atomicAdd(&stats[bz * 1024 + m0 + wm + i * 16 + qd * 4 + r2], rs[i * 4 + r2]);
    }
  }

  const long cb = bz * sC;
#pragma unroll
  for (int i = 0; i < 4; ++i) {
#pragma unroll
    for (int j = 0; j < 4; ++j) {
#pragma unroll
      for (int r2 = 0; r2 < 4; ++r2) {
        int rr = m0 + wm + i * 16 + qd * 4 + r2;  // C/D row = quad*4+reg (m89)
        int cc = n0 + wn + j * 16 + ml;           // C/D col = lane&15
        float v = acc[i][j][r2];
        if (!SMEXP) v *= alpha;
        if (COLSCALE) v *= inv[j];
        if (BIASMODE == 1) v += bias[rr];
        if (BIASMODE == 2) v += bias[cc];
        long ix = (long)rr * N + cc;
        if (RESID) v += resid[bz * sR + ix];
        if (OUTF32) ((float*)C)[cb + ix] = v;
        else        ((u16*)C)[cb + ix] = f2b(v);
      }
    }
  }
}

// ---------------------------------------------------------------------------
// GroupNorm with fused residual: spatio = x (f32) + h (bf16 conv out), then
// GroupNorm -> bf16 out TRANSPOSED to [n][p][c]. XCD-clustered work ids.
// ---------------------------------------------------------------------------
__global__ __launch_bounds__(256)
void groupnorm_resid(const u16* __restrict__ h, const float* __restrict__ x,
                     const float* __restrict__ gamma,
                     const float* __restrict__ beta, u16* __restrict__ out)
{
  const int C = 512, HW = 1024;
  const int w = (blockIdx.x & 7) * 80 + (blockIdx.x >> 3);    // XCD-cluster
  const int n = w >> 5, g = w & 31;
  const long base = ((long)n * C + g * 16) * HW;
  const float* xg = x + base;
  const u16*  hg = h + base;
  const int t = threadIdx.x;
  float s = 0.f, ss = 0.f;
  for (int ch = t; ch < 4096; ch += 256) {
    float4 u = *(const float4*)(xg + ch * 4);
    uint2 hv = *(const uint2*)(hg + ch * 4);
    float h0 = __uint_as_float(hv.x << 16);
    float h1 = __uint_as_float(hv.x & 0xffff0000u);
    float h2 = __uint_as_float(hv.y << 16);
    float h3 = __uint_as_float(hv.y & 0xffff0000u);
    float v0 = u.x + h0, v1 = u.y + h1, v2 = u.z + h2, v3 = u.w + h3;
    s += v0 + v1 + v2 + v3;
    ss += v0 * v0 + v1 * v1 + v2 * v2 + v3 * v3;
  }
#pragma unroll
  for (int off = 32; off > 0; off >>= 1) { s += __shfl_xor(s, off); ss += __shfl_xor(ss, off); }
  __shared__ float rs[4], rss[4];
  if ((t & 63) == 0) { rs[t >> 6] = s; rss[t >> 6] = ss; }
  __syncthreads();
  s  = rs[0] + rs[1] + rs[2] + rs[3];
  ss = rss[0] + rss[1] + rss[2] + rss[3];
  const float mu = s * (1.f / 16384.f);
  const float var = ss * (1.f / 16384.f) - mu * mu;
  const float rstd = rsqrtf(var + 1e-6f);
  float gm[16], bt[16];
#pragma unroll
  for (int i = 0; i < 16; ++i) {
    float ga = gamma[g * 16 + i];
    gm[i] = ga * rstd;
    bt[i] = beta[g * 16 + i] - mu * ga * rstd;
  }
  for (int p = t; p < 1024; p += 256) {
    alignas(16) u16 vals[16];
#pragma unroll
    for (int i = 0; i < 16; ++i)
      vals[i] = f2b((xg[(long)i * HW + p] + b2f(hg[(long)i * HW + p])) * gm[i] + bt[i]);
    u16* dst = out + ((long)n * HW + p) * C + g * 16;
    *(uint4*)dst       = *(const uint4*)&vals[0];
    *(uint4*)(dst + 8) = *(const uint4*)&vals[8];
  }
}

// ---------------------------------------------------------------------------
// Temporal attention (Wovt-folded): one WAVE per pixel (b,p).
// qk [20480][1024] (row = q||k per frame/pixel); "v" is hn_t itself (W7,
// [20480][512]) -- the Wvt/Wot convs are folded into the final GEMM via
// Wovt = Wot.Wvt. Output htp' = sum_s att[i][s]*hn_t[s] -> [20480][512].
// ---------------------------------------------------------------------------
__global__ __launch_bounds__(256)
void temporal_attn(const u16* __restrict__ qk, const u16* __restrict__ hn,
                   u16* __restrict__ htp)
{
  const int t = threadIdx.x;
  const int wv = t >> 6, lane = t & 63;
  const int pix = blockIdx.x * 4 + wv;      // 0..4095 = (b, p)
  const int b = pix >> 10, p = pix & 1023;
  const long fsq = 1024l * 1024;            // frame stride in qk
  const long rowq = ((long)b * 5 * 1024 + p) * 1024 + lane * 8;
  const long fsh = 1024l * 512;             // frame stride in hn/htp
  const long rowh = ((long)b * 5 * 1024 + p) * 512 + lane * 8;

  float qf[5][8], kf[5][8];
#pragma unroll
  for (int f = 0; f < 5; ++f) {
    bf16x8 qv = *(const bf16x8*)(qk + rowq + f * fsq);
    bf16x8 kv = *(const bf16x8*)(qk + rowq + f * fsq + 512);
#pragma unroll
    for (int u = 0; u < 8; ++u) { qf[f][u] = b2f((u16)qv[u]); kf[f][u] = b2f((u16)kv[u]); }
  }
  float sc[25];
#pragma unroll
  for (int i = 0; i < 5; ++i)
#pragma unroll
    for (int j = 0; j < 5; ++j) {
      float a = 0.f;
#pragma unroll
      for (int u = 0; u < 8; ++u) a += qf[i][u] * kf[j][u];
      sc[i * 5 + j] = a;
    }
#pragma unroll
  for (int m = 1; m < 64; m <<= 1)
#pragma unroll
    for (int s = 0; s < 25; ++s) sc[s] += __shfl_xor(sc[s], m);

  const float scale = 0.04419417382415922f;  // 512^-0.5
  float att[5][5];
#pragma unroll
  for (int i = 0; i < 5; ++i) {
    float m = sc[i * 5];
#pragma unroll
    for (int j = 1; j < 5; ++j) m = fmaxf(m, sc[i * 5 + j]);
    float ssum = 0.f;
#pragma unroll
    for (int j = 0; j < 5; ++j) { att[i][j] = __expf((sc[i * 5 + j] - m) * scale); ssum += att[i][j]; }
    float inv = 1.f / ssum;
#pragma unroll
    for (int j = 0; j < 5; ++j) att[i][j] *= inv;
  }

  float of[5][8];
#pragma unroll
  for (int i = 0; i < 5; ++i)
#pragma unroll
    for (int u = 0; u < 8; ++u) of[i][u] = 0.f;
#pragma unroll
  for (int s = 0; s < 5; ++s) {
    bf16x8 vvv = *(const bf16x8*)(hn + rowh + s * fsh);
#pragma unroll
    for (int u = 0; u < 8; ++u) {
      float vf = b2f((u16)vvv[u]);
#pragma unroll
      for (int i = 0; i < 5; ++i) of[i][u] += att[i][s] * vf;
    }
  }
#pragma unroll
  for (int i = 0; i < 5; ++i) {
    alignas(16) u16 ob[8];
#pragma unroll
    for (int u = 0; u < 8; ++u) ob[u] = f2b(of[i][u]);
    *(uint4*)(htp + rowh + i * fsh) = *(const uint4*)ob;
  }
}

// ---------------------------------------------------------------------------
extern "C" void kernel_launch(void* const* d_in, const int* in_sizes, int n_in,
                              void* d_out, int out_size, void* d_ws, size_t ws_size,
                              hipStream_t stream)
{
  const float* x   = (const float*)d_in[0];
  const float* wq  = (const float*)d_in[1];
  const float* bq  = (const float*)d_in[2];
  const float* wk  = (const float*)d_in[3];
  const float* bk  = (const float*)d_in[4];
  const float* wv  = (const float*)d_in[5];
  const float* bv  = (const float*)d_in[6];
  const float* wo  = (const float*)d_in[7];
  const float* bo  = (const float*)d_in[8];
  const float* wqt = (const float*)d_in[9];
  const float* bqt = (const float*)d_in[10];
  const float* wkt = (const float*)d_in[11];
  const float* bkt = (const float*)d_in[12];
  const float* wvt = (const float*)d_in[13];
  const float* bvt = (const float*)d_in[14];
  const float* wot = (const float*)d_in[15];
  const float* bot = (const float*)d_in[16];
  const float* gs  = (const float*)d_in[17];
  const float* bs  = (const float*)d_in[18];
  const float* gt  = (const float*)d_in[19];
  const float* btt = (const float*)d_in[20];

  // ws = 256 MiB. Slots W0..W7 (8 x 20 MB), weights Wt (12 x 0.5 MB), biases.
  const long U = 20l * 1024 * 512;          // elements per slot
  u16* W0 = (u16*)d_ws;
  u16* W1 = W0 + U;                          // W1..W2: qk / qk_t [20480][1024]
  u16* W3 = W0 + 3 * U;                      // vv [20][c][p]
  u16* W4 = W0 + 4 * U;                      // W4..W5 scores [20][1024][1024]
  u16* W6 = W0 + 6 * U;                      // hsp_conv [20][c][p]
  u16* W7 = W0 + 7 * U;                      // hn_t [n][p][c]
  u16* Wt = W0 + 8 * U;                      // weight slots: 0..7 converted,
  u16* wvT_b  = Wt + 8 * 262144;             // 8 = Wv^T
  u16* Wovs   = Wt + 9 * 262144;             // 9 = Wov  (z=0 of weight GEMM)
  u16* Wovt_b = Wt + 11 * 262144;            // 10 = Wvt^T, 11 = Wovt (z=1)
  float* Bf = (float*)(Wt + 12 * 262144);    // 8x512 biases; bvv@4096; bovt@4608
  float* Stats = Bf + 8192;                  // 20x1024 f32 softmax row sums
  u16* wo_b  = Wt + 3 * 262144;
  u16* wqt_b = Wt + 4 * 262144;

  const long S  = 524288;                   // 1024*512 per-image stride
  const long S2 = 1048576;                  // 1024*1024 per-image stride
  const float scale = 0.04419417382415922f; // 512^-0.5
  dim3 blk(256);

  // prep: GroupNorm_s + weight convert (+wvT,+wvtT) + biases + bvv/bovt + stats
  prep<<<1756, blk, 0, stream>>>(x, gs, bs, W0,
                                 wq, wk, wv, wo, wqt, wkt, wvt, wot,
                                 bq, bk, bv, bo, bqt, bkt, bvt, bot, Wt, Bf);

  // Batched weight GEMM (z=2): z=0 Wov = Wo.Wv; z=1 Wovt = Wot.Wvt
  //   A: slot3 (wo) -> slot7 (wot), stride 4 slots; Bt: slot8 -> slot10;
  //   C: slot9 -> slot11.
  gemm_bt<0, 0, 0, 0, 0><<<dim3(4, 4, 2), blk, 0, stream>>>(
      wo_b, 4 * 262144, 512, wvT_b, 2 * 262144, 512, Wovs, 2 * 262144,
      nullptr, nullptr, 0, 512, 512, 1.f, nullptr);

  // qk fused: M=20480, N=1024 (wq||wk), K=512 -> W1W2 [20480][1024]
  gemm_bt<0, 2, 0, 0, 0><<<dim3(8, 160, 1), blk, 0, stream>>>(
      W0, 0, 512, Wt, 0, 512, W1, 0, Bf, nullptr, 0, 1024, 512, 1.f, nullptr);
  // vv = Wov.hn^T + Wo.bv: batched z=20, M=c'(512), N=p(1024) -> W3 [20][c][p]
  gemm_bt<0, 1, 0, 0, 0><<<dim3(8, 4, 20), blk, 0, stream>>>(
      Wovs, 0, 512, W0, S, 512, W3, S, Bf + 4096, nullptr, 0, 1024, 512, 1.f, Stats);
  // att_exp = exp(scale * q.k^T) -> W4W5; row sums accumulated into Stats
  gemm_bt<0, 0, 0, 1, 0><<<dim3(8, 8, 20), blk, 0, stream>>>(
      W1, S2, 1024, W1 + 512, S2, 1024, W4, S2, nullptr, nullptr, 0, 1024, 512, scale, Stats);
  // hsp_conv = (vv.att_exp^T) * inv[pq] + bo: z=20, M=c', N=pq, K=pk -> W6
  gemm_bt<0, 1, 0, 0, 1><<<dim3(8, 4, 20), blk, 0, stream>>>(
      W3, S, 1024, W4, S2, 1024, W6, S, Bf + 1536, nullptr, 0, 1024, 1024, 1.f, Stats);
  // hn_t = GroupNorm_t(x + W6) -> W7 [n][p][c]  (resid fused here)
  groupnorm_resid<<<640, blk, 0, stream>>>(W6, x, gt, btt, W7);
  // qk_t fused: M=20480, N=1024 (wqt||wkt), K=512 -> W1W2 [20480][1024]
  //   (v_t folded into final GEMM via Wovt -- was N=1536)
  gemm_bt<0, 2, 0, 0, 0><<<dim3(8, 160, 1), blk, 0, stream>>>(
      W7, 0, 512, wqt_b, 0, 512, W1, 0, Bf + 2048, nullptr, 0, 1024, 512, 1.f, nullptr);
  // per-pixel 5x5 temporal attention on hn_t directly -> W0 htp' [20480][512]
  temporal_attn<<<1024, blk, 0, stream>>>(W1, W7, W0);
  // out = x + Wovt.htp' + (Wot.bvt + bot) -> d_out f32, z=20
  gemm_bt<1, 1, 1, 0, 0><<<dim3(8, 4, 20), blk, 0, stream>>>(
      Wovt_b, 0, 512, W0, S, 512, (float*)d_out, S, Bf + 4608, x, S, 1024, 512, 1.f, nullptr);
}

// Round 10
// 390.385 us; speedup vs baseline: 1.3537x; 1.0038x over previous
//
#include <hip/hip_runtime.h>
#include <hip/hip_bf16.h>
#include <stdint.h>

typedef unsigned short u16;
typedef __attribute__((ext_vector_type(8))) short bf16x8;
typedef __attribute__((ext_vector_type(4))) float f32x4;

#define DI __device__ __forceinline__

DI float b2f(u16 u) { return __uint_as_float(((uint32_t)u) << 16); }
DI u16 f2b(float f) {
  uint32_t u = __float_as_uint(f);
  u += 0x7fff + ((u >> 16) & 1);   // RNE
  return (u16)(u >> 16);
}

DI void gld_lds16(const u16* g, u16* l) {
  __builtin_amdgcn_global_load_lds((const __attribute__((address_space(1))) void*)g,
                                   (__attribute__((address_space(3))) void*)l,
                                   16, 0, 0);
}

// ---------------------------------------------------------------------------
// PREP (one launch):
//  [0,640)      GroupNorm_s(x) -> W0 [n][p][c] (XCD-clustered work ids)
//  [640,1664)   convert 8 weight matrices f32->bf16
//               (wv transposed -> slot 8; wvt transposed -> slot 10)
//  [1664,1672)  pack 8 biases (f32)
//  [1672,1674)  bvv  = Wo.bv            (f32) at bdst+4096
//  [1674,1676)  bovt = Wot.bvt + bot    (f32) at bdst+4608
//  [1676,1756)  zero softmax stats (20x1024 f32) at bdst+8192
// ---------------------------------------------------------------------------
__global__ __launch_bounds__(256)
void prep(const float* __restrict__ x, const float* __restrict__ gamma,
          const float* __restrict__ beta, u16* __restrict__ gnout,
          const float* __restrict__ w0, const float* __restrict__ w1,
          const float* __restrict__ w2, const float* __restrict__ w3,
          const float* __restrict__ w4, const float* __restrict__ w5,
          const float* __restrict__ w6, const float* __restrict__ w7,
          const float* __restrict__ b0, const float* __restrict__ b1,
          const float* __restrict__ b2, const float* __restrict__ b3,
          const float* __restrict__ b4, const float* __restrict__ b5,
          const float* __restrict__ b6, const float* __restrict__ b7,
          u16* __restrict__ dst, float* __restrict__ bdst)
{
  const int t = threadIdx.x;
  if (blockIdx.x < 640) {                   // ---- GroupNorm_s ----
    const int w = (blockIdx.x & 7) * 80 + (blockIdx.x >> 3);  // XCD-cluster
    const int n = w >> 5, g = w & 31;
    const int C = 512, HW = 1024;
    const float* xg = x + ((long)n * C + g * 16) * HW;
    float s = 0.f, ss = 0.f;
    for (int ch = t; ch < 4096; ch += 256) {
      float4 u = *(const float4*)(xg + ch * 4);
      s += u.x + u.y + u.z + u.w;
      ss += u.x * u.x + u.y * u.y + u.z * u.z + u.w * u.w;
    }
#pragma unroll
    for (int off = 32; off > 0; off >>= 1) { s += __shfl_xor(s, off); ss += __shfl_xor(ss, off); }
    __shared__ float rs[4], rss[4];
    if ((t & 63) == 0) { rs[t >> 6] = s; rss[t >> 6] = ss; }
    __syncthreads();
    s  = rs[0] + rs[1] + rs[2] + rs[3];
    ss = rss[0] + rss[1] + rss[2] + rss[3];
    const float mu = s * (1.f / 16384.f);
    const float var = ss * (1.f / 16384.f) - mu * mu;
    const float rstd = rsqrtf(var + 1e-6f);
    float gm[16], bt[16];
#pragma unroll
    for (int i = 0; i < 16; ++i) {
      float ga = gamma[g * 16 + i];
      gm[i] = ga * rstd;
      bt[i] = beta[g * 16 + i] - mu * ga * rstd;
    }
    for (int p = t; p < 1024; p += 256) {
      alignas(16) u16 vals[16];
#pragma unroll
      for (int i = 0; i < 16; ++i)
        vals[i] = f2b(xg[(long)i * HW + p] * gm[i] + bt[i]);
      u16* dp = gnout + ((long)n * HW + p) * C + g * 16;
      *(uint4*)dp       = *(const uint4*)&vals[0];
      *(uint4*)(dp + 8) = *(const uint4*)&vals[8];
    }
    return;
  }
  const int sb = blockIdx.x - 640;          // ---- setup ----
  if (sb >= 1036) {                         // zero softmax stats
    bdst[8192 + (sb - 1036) * 256 + t] = 0.f;
    return;
  }
  if (sb >= 1034) {                         // bovt = Wot.bvt + bot
    const int a = (sb - 1034) * 256 + t;
    float acc = 0.f;
    for (int c = 0; c < 512; ++c) acc += w7[a * 512 + c] * b6[c];
    bdst[4608 + a] = acc + b7[a];
    return;
  }
  if (sb >= 1032) {                         // bvv = Wo . bv
    const int a = (sb - 1032) * 256 + t;
    float acc = 0.f;
    for (int c = 0; c < 512; ++c) acc += w3[a * 512 + c] * b2[c];
    bdst[4096 + a] = acc;
    return;
  }
  if (sb >= 1024) {                         // biases
    const float* bs8[8] = {b0, b1, b2, b3, b4, b5, b6, b7};
    const int a = sb - 1024;
    bdst[a * 512 + t] = bs8[a][t];
    bdst[a * 512 + t + 256] = bs8[a][t + 256];
    return;
  }
  const float* srcs[8] = {w0, w1, w2, w3, w4, w5, w6, w7};
  const int mat = sb >> 7;
  const int i = (((sb & 127) << 8) + t) * 8;
  const float* s = srcs[mat];
  float4 a = *(const float4*)(s + i);
  float4 b = *(const float4*)(s + i + 4);
  alignas(16) u16 v[8] = {f2b(a.x), f2b(a.y), f2b(a.z), f2b(a.w),
                          f2b(b.x), f2b(b.y), f2b(b.z), f2b(b.w)};
  *(uint4*)(dst + (long)mat * 262144 + i) = *(const uint4*)v;
  if (mat == 2 || mat == 6) {               // wv -> slot 8, wvt -> slot 10
    const int slot = (mat == 2) ? 8 : 10;
    const int row = i >> 9, col = i & 511;
#pragma unroll
    for (int j = 0; j < 8; ++j) dst[(long)slot * 262144 + (col + j) * 512 + row] = v[j];
  }
}

// ---------------------------------------------------------------------------
// Shared GEMM body: BM=BN=128, BK=32, 256 threads (4 waves 2x2 of 64x64),
// 16x16x32 bf16 MFMA, XOR-swizzled LDS (0 conflicts), LDS double-buffer.
// Caller resolves batch pointers and tile (m0,n0). Epilogue uses per-row
// base addressing (16 long-muls, not 64) and pre-loaded column biases.
// ---------------------------------------------------------------------------
template<int OUTF32, int BIASMODE, int RESID, int SMEXP, int COLSCALE>
DI void gemm_body(const u16* __restrict__ Ab, long lda,
                  const u16* __restrict__ Bb, long ldb,
                  void* __restrict__ C, long cb,
                  const float* __restrict__ bias,
                  const float* __restrict__ resid, long rb,
                  int N, int K, float alpha,
                  float* __restrict__ stats, long stb,
                  int m0, int n0, u16* lA, u16* lB)
{
  const int t = threadIdx.x;
  const int lane = t & 63;
  const int wid = t >> 6;
  const int row = t >> 2;                              // 0..63
  const int kc  = (((t & 3) ^ ((t >> 3) & 3)) << 3);   // swizzled staged chunk

  f32x4 acc[4][4];
#pragma unroll
  for (int i = 0; i < 4; ++i)
#pragma unroll
    for (int j = 0; j < 4; ++j) acc[i][j] = (f32x4){0.f, 0.f, 0.f, 0.f};

  const int ml = lane & 15, qd = lane >> 4;
  const int koff = ((qd ^ ((ml >> 1) & 3)) << 3);      // swizzled read offset
  const int wm = (wid >> 1) * 64, wn = (wid & 1) * 64;

  auto stage = [&](int bsel, int k0) {
    const u16* Ap = Ab + (long)(m0 + row) * lda + (k0 + kc);
    const u16* Bp = Bb + (long)(n0 + row) * ldb + (k0 + kc);
    u16* la = lA + bsel * 4096 + wid * 512;
    u16* lb = lB + bsel * 4096 + wid * 512;
    gld_lds16(Ap, la);
    gld_lds16(Ap + 64 * lda, la + 2048);
    gld_lds16(Bp, lb);
    gld_lds16(Bp + 64 * ldb, lb + 2048);
  };

  const int niter = K >> 5;
  stage(0, 0);
  for (int i = 0; i < niter; ++i) {
    __syncthreads();                       // drains buf[i&1] prefetch
    if (i + 1 < niter) stage((i + 1) & 1, (i + 1) << 5);  // overlaps MFMA below
    const u16* la = lA + (i & 1) * 4096;
    const u16* lb = lB + (i & 1) * 4096;
    bf16x8 af[4], bfr[4];
#pragma unroll
    for (int x = 0; x < 4; ++x)
      af[x] = *(const bf16x8*)&la[(wm + x * 16 + ml) * 32 + koff];
#pragma unroll
    for (int y = 0; y < 4; ++y)
      bfr[y] = *(const bf16x8*)&lb[(wn + y * 16 + ml) * 32 + koff];
#pragma unroll
    for (int x = 0; x < 4; ++x)
#pragma unroll
      for (int y = 0; y < 4; ++y)
        acc[x][y] = __builtin_amdgcn_mfma_f32_16x16x32_bf16(af[x], bfr[y], acc[x][y], 0, 0, 0);
  }

  float inv[4], bcol[4];
  if (COLSCALE) {
#pragma unroll
    for (int j = 0; j < 4; ++j)
      inv[j] = 1.f / stats[stb + n0 + wn + j * 16 + ml];
  }
  if (BIASMODE == 2) {
#pragma unroll
    for (int j = 0; j < 4; ++j) bcol[j] = bias[n0 + wn + j * 16 + ml];
  }
  if (SMEXP) {
    float rs[16];
#pragma unroll
    for (int s = 0; s < 16; ++s) rs[s] = 0.f;
#pragma unroll
    for (int i = 0; i < 4; ++i)
#pragma unroll
      for (int j = 0; j < 4; ++j)
#pragma unroll
        for (int r2 = 0; r2 < 4; ++r2) {
          float e = __expf(acc[i][j][r2] * alpha);
          acc[i][j][r2] = e;
          rs[i * 4 + r2] += e;
        }
#pragma unroll
    for (int m = 1; m < 16; m <<= 1)
#pragma unroll
      for (int s = 0; s < 16; ++s) rs[s] += __shfl_xor(rs[s], m);
    if (ml == 0) {
#pragma unroll
      for (int i = 0; i < 4; ++i)
#pragma unroll
        for (int r2 = 0; r2 < 4; ++r2)
          atomicAdd(&stats[stb + m0 + wm + i * 16 + qd * 4 + r2], rs[i * 4 + r2]);
    }
  }

#pragma unroll
  for (int i = 0; i < 4; ++i) {
#pragma unroll
    for (int r2 = 0; r2 < 4; ++r2) {
      const int rr = m0 + wm + i * 16 + qd * 4 + r2;  // C/D row = quad*4+reg
      const float brow = (BIASMODE == 1) ? bias[rr] : 0.f;
      const long base = (long)rr * N + n0 + wn + ml;  // col = lane&15 (+j*16)
#pragma unroll
      for (int j = 0; j < 4; ++j) {
        float v = acc[i][j][r2];
        if (!SMEXP) v *= alpha;
        if (COLSCALE) v *= inv[j];
        if (BIASMODE == 1) v += brow;
        if (BIASMODE == 2) v += bcol[j];
        const long ix = base + j * 16;
        if (RESID) v += resid[rb + ix];
        if (OUTF32) ((float*)C)[cb + ix] = v;
        else        ((u16*)C)[cb + ix] = f2b(v);
      }
    }
  }
}

// Generic batched GEMM with z-clustered XCD remap (verified R7).
template<int OUTF32, int BIASMODE, int RESID, int SMEXP, int COLSCALE>
__global__ __launch_bounds__(256)
void gemm_bt(const u16* __restrict__ A, long sA, long lda,
             const u16* __restrict__ B, long sB, long ldb,
             void* __restrict__ C, long sC,
             const float* __restrict__ bias,
             const float* __restrict__ resid, long sR,
             int N, int K, float alpha, float* __restrict__ stats)
{
  __shared__ u16 lA[2 * 128 * 32];
  __shared__ u16 lB[2 * 128 * 32];
  const uint32_t nx = gridDim.x, ny = gridDim.y;
  const uint32_t tpz = nx * ny;
  const uint32_t nblk = tpz * gridDim.z;
  const uint32_t g = ((uint32_t)blockIdx.z * ny + blockIdx.y) * nx + blockIdx.x;
  const uint32_t idx = (g & 7u) * (nblk >> 3) + (g >> 3);
  const uint32_t bz = idx / tpz;
  const uint32_t r   = idx - bz * tpz;
  const int m0 = (int)(r / nx) * 128, n0 = (int)(r % nx) * 128;
  gemm_body<OUTF32, BIASMODE, RESID, SMEXP, COLSCALE>(
      A + bz * sA, lda, B + bz * sB, ldb, C, bz * sC, bias, resid, bz * sR,
      N, K, alpha, stats, (long)bz * 1024, m0, n0, lA, lB);
}

// ---------------------------------------------------------------------------
// Merged qk || vv launch (both depend only on prep+Wov, mutually independent):
//  blocks [0,1280):   qk = hn.Wqk^T + bias_col  (M=20480, N=1024, K=512)
//  blocks [1280,1920): vv = Wov.hn^T + bvv      (z=20, M=512, N=1024, K=512)
// 1280%8==0 keeps XCD parity for both partitions' z-clustered remaps.
// vv fills qk's dispatch/tail bubbles -> combined < sum of parts.
// ---------------------------------------------------------------------------
__global__ __launch_bounds__(256)
void gemm_qkvv(const u16* __restrict__ hn, const u16* __restrict__ Wqk,
               u16* __restrict__ qkout, const float* __restrict__ bqk,
               const u16* __restrict__ Wov, u16* __restrict__ vvout,
               const float* __restrict__ bvv)
{
  __shared__ u16 lA[2 * 128 * 32];
  __shared__ u16 lB[2 * 128 * 32];
  const long S = 524288;
  const uint32_t g = blockIdx.x;
  if (g < 1280) {                           // ---- qk ----
    const uint32_t idx = (g & 7u) * 160 + (g >> 3);
    const int m0 = (int)(idx >> 3) * 128, n0 = (int)(idx & 7u) * 128;
    gemm_body<0, 2, 0, 0, 0>(hn, 512, Wqk, 512, qkout, 0, bqk, nullptr, 0,
                             1024, 512, 1.f, nullptr, 0, m0, n0, lA, lB);
  } else {                                  // ---- vv ----
    const uint32_t gg = g - 1280;           // gg&7 == g&7 (1280%8==0)
    const uint32_t idx = (gg & 7u) * 80 + (gg >> 3);
    const uint32_t bz = idx >> 5;           // /32 tiles per z
    const uint32_t r = idx & 31u;
    const int m0 = (int)(r >> 3) * 128, n0 = (int)(r & 7u) * 128;
    gemm_body<0, 1, 0, 0, 0>(Wov, 512, hn + (long)bz * S, 512, vvout,
                             (long)bz * S, bvv, nullptr, 0,
                             1024, 512, 1.f, nullptr, 0, m0, n0, lA, lB);
  }
}

// ---------------------------------------------------------------------------
// GroupNorm with fused residual: spatio = x (f32) + h (bf16 conv out), then
// GroupNorm -> bf16 out TRANSPOSED to [n][p][c]. XCD-clustered work ids.
// ---------------------------------------------------------------------------
__global__ __launch_bounds__(256)
void groupnorm_resid(const u16* __restrict__ h, const float* __restrict__ x,
                     const float* __restrict__ gamma,
                     const float* __restrict__ beta, u16* __restrict__ out)
{
  const int C = 512, HW = 1024;
  const int w = (blockIdx.x & 7) * 80 + (blockIdx.x >> 3);    // XCD-cluster
  const int n = w >> 5, g = w & 31;
  const long base = ((long)n * C + g * 16) * HW;
  const float* xg = x + base;
  const u16*  hg = h + base;
  const int t = threadIdx.x;
  float s = 0.f, ss = 0.f;
  for (int ch = t; ch < 4096; ch += 256) {
    float4 u = *(const float4*)(xg + ch * 4);
    uint2 hv = *(const uint2*)(hg + ch * 4);
    float h0 = __uint_as_float(hv.x << 16);
    float h1 = __uint_as_float(hv.x & 0xffff0000u);
    float h2 = __uint_as_float(hv.y << 16);
    float h3 = __uint_as_float(hv.y & 0xffff0000u);
    float v0 = u.x + h0, v1 = u.y + h1, v2 = u.z + h2, v3 = u.w + h3;
    s += v0 + v1 + v2 + v3;
    ss += v0 * v0 + v1 * v1 + v2 * v2 + v3 * v3;
  }
#pragma unroll
  for (int off = 32; off > 0; off >>= 1) { s += __shfl_xor(s, off); ss += __shfl_xor(ss, off); }
  __shared__ float rs[4], rss[4];
  if ((t & 63) == 0) { rs[t >> 6] = s; rss[t >> 6] = ss; }
  __syncthreads();
  s  = rs[0] + rs[1] + rs[2] + rs[3];
  ss = rss[0] + rss[1] + rss[2] + rss[3];
  const float mu = s * (1.f / 16384.f);
  const float var = ss * (1.f / 16384.f) - mu * mu;
  const float rstd = rsqrtf(var + 1e-6f);
  float gm[16], bt[16];
#pragma unroll
  for (int i = 0; i < 16; ++i) {
    float ga = gamma[g * 16 + i];
    gm[i] = ga * rstd;
    bt[i] = beta[g * 16 + i] - mu * ga * rstd;
  }
  for (int p = t; p < 1024; p += 256) {
    alignas(16) u16 vals[16];
#pragma unroll
    for (int i = 0; i < 16; ++i)
      vals[i] = f2b((xg[(long)i * HW + p] + b2f(hg[(long)i * HW + p])) * gm[i] + bt[i]);
    u16* dst = out + ((long)n * HW + p) * C + g * 16;
    *(uint4*)dst       = *(const uint4*)&vals[0];
    *(uint4*)(dst + 8) = *(const uint4*)&vals[8];
  }
}

// ---------------------------------------------------------------------------
// Temporal attention (Wovt-folded): one WAVE per pixel (b,p).
// qk [20480][1024]; "v" is hn_t itself (W7, [20480][512]); output
// htp' = sum_s att[i][s]*hn_t[s] -> [20480][512].
// ---------------------------------------------------------------------------
__global__ __launch_bounds__(256)
void temporal_attn(const u16* __restrict__ qk, const u16* __restrict__ hn,
                   u16* __restrict__ htp)
{
  const int t = threadIdx.x;
  const int wv = t >> 6, lane = t & 63;
  const int pix = blockIdx.x * 4 + wv;      // 0..4095 = (b, p)
  const int b = pix >> 10, p = pix & 1023;
  const long fsq = 1024l * 1024;            // frame stride in qk
  const long rowq = ((long)b * 5 * 1024 + p) * 1024 + lane * 8;
  const long fsh = 1024l * 512;             // frame stride in hn/htp
  const long rowh = ((long)b * 5 * 1024 + p) * 512 + lane * 8;

  float qf[5][8], kf[5][8];
#pragma unroll
  for (int f = 0; f < 5; ++f) {
    bf16x8 qv = *(const bf16x8*)(qk + rowq + f * fsq);
    bf16x8 kv = *(const bf16x8*)(qk + rowq + f * fsq + 512);
#pragma unroll
    for (int u = 0; u < 8; ++u) { qf[f][u] = b2f((u16)qv[u]); kf[f][u] = b2f((u16)kv[u]); }
  }
  float sc[25];
#pragma unroll
  for (int i = 0; i < 5; ++i)
#pragma unroll
    for (int j = 0; j < 5; ++j) {
      float a = 0.f;
#pragma unroll
      for (int u = 0; u < 8; ++u) a += qf[i][u] * kf[j][u];
      sc[i * 5 + j] = a;
    }
#pragma unroll
  for (int m = 1; m < 64; m <<= 1)
#pragma unroll
    for (int s = 0; s < 25; ++s) sc[s] += __shfl_xor(sc[s], m);

  const float scale = 0.04419417382415922f;  // 512^-0.5
  float att[5][5];
#pragma unroll
  for (int i = 0; i < 5; ++i) {
    float m = sc[i * 5];
#pragma unroll
    for (int j = 1; j < 5; ++j) m = fmaxf(m, sc[i * 5 + j]);
    float ssum = 0.f;
#pragma unroll
    for (int j = 0; j < 5; ++j) { att[i][j] = __expf((sc[i * 5 + j] - m) * scale); ssum += att[i][j]; }
    float inv = 1.f / ssum;
#pragma unroll
    for (int j = 0; j < 5; ++j) att[i][j] *= inv;
  }

  float of[5][8];
#pragma unroll
  for (int i = 0; i < 5; ++i)
#pragma unroll
    for (int u = 0; u < 8; ++u) of[i][u] = 0.f;
#pragma unroll
  for (int s = 0; s < 5; ++s) {
    bf16x8 vvv = *(const bf16x8*)(hn + rowh + s * fsh);
#pragma unroll
    for (int u = 0; u < 8; ++u) {
      float vf = b2f((u16)vvv[u]);
#pragma unroll
      for (int i = 0; i < 5; ++i) of[i][u] += att[i][s] * vf;
    }
  }
#pragma unroll
  for (int i = 0; i < 5; ++i) {
    alignas(16) u16 ob[8];
#pragma unroll
    for (int u = 0; u < 8; ++u) ob[u] = f2b(of[i][u]);
    *(uint4*)(htp + rowh + i * fsh) = *(const uint4*)ob;
  }
}

// ---------------------------------------------------------------------------
extern "C" void kernel_launch(void* const* d_in, const int* in_sizes, int n_in,
                              void* d_out, int out_size, void* d_ws, size_t ws_size,
                              hipStream_t stream)
{
  const float* x   = (const float*)d_in[0];
  const float* wq  = (const float*)d_in[1];
  const float* bq  = (const float*)d_in[2];
  const float* wk  = (const float*)d_in[3];
  const float* bk  = (const float*)d_in[4];
  const float* wv  = (const float*)d_in[5];
  const float* bv  = (const float*)d_in[6];
  const float* wo  = (const float*)d_in[7];
  const float* bo  = (const float*)d_in[8];
  const float* wqt = (const float*)d_in[9];
  const float* bqt = (const float*)d_in[10];
  const float* wkt = (const float*)d_in[11];
  const float* bkt = (const float*)d_in[12];
  const float* wvt = (const float*)d_in[13];
  const float* bvt = (const float*)d_in[14];
  const float* wot = (const float*)d_in[15];
  const float* bot = (const float*)d_in[16];
  const float* gs  = (const float*)d_in[17];
  const float* bs  = (const float*)d_in[18];
  const float* gt  = (const float*)d_in[19];
  const float* btt = (const float*)d_in[20];

  // ws = 256 MiB. Slots W0..W7 (8 x 20 MB), weights Wt (12 x 0.5 MB), biases.
  const long U = 20l * 1024 * 512;          // elements per slot
  u16* W0 = (u16*)d_ws;
  u16* W1 = W0 + U;                          // W1..W2: qk / qk_t [20480][1024]
  u16* W3 = W0 + 3 * U;                      // vv [20][c][p]
  u16* W4 = W0 + 4 * U;                      // W4..W5 scores [20][1024][1024]
  u16* W6 = W0 + 6 * U;                      // hsp_conv [20][c][p]
  u16* W7 = W0 + 7 * U;                      // hn_t [n][p][c]
  u16* Wt = W0 + 8 * U;                      // weight slots: 0..7 converted,
  u16* wvT_b  = Wt + 8 * 262144;             // 8 = Wv^T
  u16* Wovs   = Wt + 9 * 262144;             // 9 = Wov  (z=0 of weight GEMM)
  u16* Wovt_b = Wt + 11 * 262144;            // 10 = Wvt^T, 11 = Wovt (z=1)
  float* Bf = (float*)(Wt + 12 * 262144);    // 8x512 biases; bvv@4096; bovt@4608
  float* Stats = Bf + 8192;                  // 20x1024 f32 softmax row sums
  u16* wo_b  = Wt + 3 * 262144;
  u16* wqt_b = Wt + 4 * 262144;

  const long S  = 524288;                   // 1024*512 per-image stride
  const long S2 = 1048576;                  // 1024*1024 per-image stride
  const float scale = 0.04419417382415922f; // 512^-0.5
  dim3 blk(256);

  // prep: GroupNorm_s + weight convert (+wvT,+wvtT) + biases + bvv/bovt + stats
  prep<<<1756, blk, 0, stream>>>(x, gs, bs, W0,
                                 wq, wk, wv, wo, wqt, wkt, wvt, wot,
                                 bq, bk, bv, bo, bqt, bkt, bvt, bot, Wt, Bf);

  // Batched weight GEMM (z=2): z=0 Wov = Wo.Wv; z=1 Wovt = Wot.Wvt
  gemm_bt<0, 0, 0, 0, 0><<<dim3(4, 4, 2), blk, 0, stream>>>(
      wo_b, 4 * 262144, 512, wvT_b, 2 * 262144, 512, Wovs, 2 * 262144,
      nullptr, nullptr, 0, 512, 512, 1.f, nullptr);

  // qk || vv merged (independent after prep+Wov): 1280 + 640 blocks
  gemm_qkvv<<<1920, blk, 0, stream>>>(W0, Wt, W1, Bf, Wovs, W3, Bf + 4096);

  // att_exp = exp(scale * q.k^T) -> W4W5; row sums accumulated into Stats
  gemm_bt<0, 0, 0, 1, 0><<<dim3(8, 8, 20), blk, 0, stream>>>(
      W1, S2, 1024, W1 + 512, S2, 1024, W4, S2, nullptr, nullptr, 0, 1024, 512, scale, Stats);
  // hsp_conv = (vv.att_exp^T) * inv[pq] + bo: z=20, M=c', N=pq, K=pk -> W6
  gemm_bt<0, 1, 0, 0, 1><<<dim3(8, 4, 20), blk, 0, stream>>>(
      W3, S, 1024, W4, S2, 1024, W6, S, Bf + 1536, nullptr, 0, 1024, 1024, 1.f, Stats);
  // hn_t = GroupNorm_t(x + W6) -> W7 [n][p][c]  (resid fused here)
  groupnorm_resid<<<640, blk, 0, stream>>>(W6, x, gt, btt, W7);
  // qk_t fused: M=20480, N=1024 (wqt||wkt), K=512 -> W1W2 [20480][1024]
  gemm_bt<0, 2, 0, 0, 0><<<dim3(8, 160, 1), blk, 0, stream>>>(
      W7, 0, 512, wqt_b, 0, 512, W1, 0, Bf + 2048, nullptr, 0, 1024, 512, 1.f, nullptr);
  // per-pixel 5x5 temporal attention on hn_t directly -> W0 htp' [20480][512]
  temporal_attn<<<1024, blk, 0, stream>>>(W1, W7, W0);
  // out = x + Wovt.htp' + (Wot.bvt + bot) -> d_out f32, z=20
  gemm_bt<1, 1, 1, 0, 0><<<dim3(8, 4, 20), blk, 0, stream>>>(
      Wovt_b, 0, 512, W0, S, 512, (float*)d_out, S, Bf + 4608, x, S, 1024, 512, 1.f, nullptr);
}